// Round 9
// baseline (621.974 us; speedup 1.0000x reference)
//
#include <hip/hip_runtime.h>
#include <cmath>

#define NT 256
#define BT 128

// ---------------- ws float-offsets for constant tables ----------------
#define OFF_W60   0          // 19*60 complex
#define OFF_E20   2280       // legacy
#define OFF_E12   2320       // legacy
#define OFF_W2J   2344       // 12 floats
#define OFF_DM1   2356       // 100*60
#define OFF_Y1B   8356       // 100*24 complex
#define OFF_D1R   13156      // [j=20][flat=1330] (2l+1)*d^l at beta1
#define OFF_DM2   39756      // [j=20][k2=286]  w1[j]*d^l(beta1_j)
#define OFF_Y2B   45476      // 286*192 complex
#define OFF_D2R   155300     // [j=12][flat=286] (2l+1)*d^l at beta2
#define OFF_T19U  158732     // 20x19 complex [c][n] e^{+2pi i n c/20}
#define OFF_T11V  159492     // 11x20 complex [r][c] e^{-2pi i (r-5) c/20}
#define OFF_T12U  159932     // 12x11 complex [c][n] e^{+2pi i n c/12}
#define OFF_TABA  160196     // 1330 int packed (legacy, full Z table)
#define OFF_TABB  161526     // 286 int packed
#define OFF_TH19  161812     // 20x10 complex [a][mm] f*e^{+2pi i mm a/20}, f=1 (mm=0) else 2
#define OFF_TH12  162212     // 12x6 complex [a][mm] f*e^{+2pi i mm a/12}
#define OFF_TABH  162356     // 146 int packed (l | loc<<8): half items per l
#define OFF_TAH1  162504     // 715 int packed (l | mm<<8 | ni<<16): upper-half Z items
#define OFF_END   163220
#define N_INIT    103729

__constant__ int c_ZB1[10] = {0,1,10,35,84,165,286,455,680,969};
__constant__ int c_ZBH[10] = {0,1,7,22,50,95,161,252,372,525};  // upper-half Z offsets, total 715
__constant__ int c_ZB2[6]  = {0,1,10,35,84,165};
__constant__ int c_BOFF[6] = {0,22,208,718,1712,3350};  // padded row offsets for k_Z2 LDS

// wave-local sync: per-wave-private LDS phase buffers only.
__device__ inline void wsync() {
    __asm__ volatile("" ::: "memory");
    __builtin_amdgcn_s_waitcnt(0xC07F);   // vmcnt=63, expcnt=7, lgkmcnt=0
    __builtin_amdgcn_wave_barrier();
    __asm__ volatile("" ::: "memory");
}

// ---------------- fp64 helpers for the init kernel ----------------
__device__ inline double dipow(double x, int e) {
    double r = 1.0;
    for (int i = 0; i < e; ++i) r *= x;
    return r;
}

__device__ double wigd(const double* F, int l, int mp, int m, double beta) {
    double cb = cos(beta * 0.5), sb = sin(beta * 0.5);
    int smin = m - mp; if (smin < 0) smin = 0;
    int smax = l + m;  if (l - mp < smax) smax = l - mp;
    double pref = sqrt(F[l+mp] * F[l-mp] * F[l+m] * F[l-m]);
    double sum = 0.0;
    for (int s = smin; s <= smax; ++s) {
        double t = pref / (F[l+m-s] * F[s] * F[mp-m+s] * F[l-mp-s]);
        t *= dipow(cb, 2*l + m - mp - 2*s) * dipow(sb, mp - m + 2*s);
        sum += ((mp - m + s) & 1) ? -t : t;
    }
    return sum;
}

__device__ double qwj(int bnd, int j) {
    const double PI = 3.14159265358979323846;
    double theta = PI * (2*j + 1) / (4.0 * bnd);
    double s = 0.0;
    for (int k = 0; k < bnd; ++k) s += sin(theta * (2*k + 1)) / (2*k + 1);
    return 2.0 / bnd * sin(theta) * s;
}

// ---------------- init ----------------
__global__ void k_init(float* __restrict__ ws) {
    int idx = blockIdx.x * blockDim.x + threadIdx.x;
    if (idx >= N_INIT) return;
    double F[20];
    F[0] = 1.0;
    #pragma unroll
    for (int i = 1; i < 20; ++i) F[i] = F[i-1] * i;
    const double PI = 3.14159265358979323846;

    if (idx < 1140) {                       // W60
        int r = idx / 60, a = idx % 60;
        double ang = -2.0 * PI * (double)((r - 9) * a) / 60.0;
        ws[OFF_W60 + 2*idx]     = (float)cos(ang);
        ws[OFF_W60 + 2*idx + 1] = (float)sin(ang);
    } else if (idx < 1160) {
        int t = idx - 1140;
        double ang = 2.0 * PI * t / 20.0;
        ws[OFF_E20 + 2*t]     = (float)cos(ang);
        ws[OFF_E20 + 2*t + 1] = (float)sin(ang);
    } else if (idx < 1172) {
        int t = idx - 1160;
        double ang = 2.0 * PI * t / 12.0;
        ws[OFF_E12 + 2*t]     = (float)cos(ang);
        ws[OFF_E12 + 2*t + 1] = (float)sin(ang);
    } else if (idx < 1184) {                // W2J
        int j = idx - 1172;
        ws[OFF_W2J + j] = (float)qwj(6, j);
    } else if (idx < 7184) {                // DM1[k][j]
        int e = idx - 1184; int k = e / 60, j = e % 60;
        int l = 0; while ((l + 1) * (l + 1) <= k) ++l;
        int m = k - l*l - l;
        double beta = PI * (2*j + 1) / 120.0;
        ws[OFF_DM1 + e] = (float)(qwj(30, j) * wigd(F, l, m, 0, beta));
    } else if (idx < 9584) {                // Y1B
        int e = idx - 7184; int k = e / 24, g = e % 24;
        int l = 0; while ((l + 1) * (l + 1) <= k) ++l;
        int m = k - l*l - l;
        int bi = g / 8, ai = g % 8;
        double beta  = (bi + 1) * (PI / 8.0) / 3.0;
        double alpha = 2.0 * PI * ai / 8.0;
        double d = wigd(F, l, m, 0, beta);
        double ph = -(double)m * alpha;
        ws[OFF_Y1B + 2*e]     = (float)(d * cos(ph));
        ws[OFF_Y1B + 2*e + 1] = (float)(d * sin(ph));
    } else if (idx < 36184) {               // D1R [j][flat], prescaled by (2l+1)
        int e = idx - 9584; int j = e / 1330, t = e % 1330;
        int l = 0; while (l < 9 && t >= c_ZB1[l+1]) ++l;
        int L = 2*l + 1, loc = t - c_ZB1[l];
        int mi = loc / L, ni = loc % L;
        double beta = PI * (2*j + 1) / 40.0;
        ws[OFF_D1R + e] = (float)((double)L * wigd(F, l, mi - l, ni - l, beta));
    } else if (idx < 41904) {               // DM2 [j][k2]
        int e = idx - 36184; int j = e / 286, k2 = e % 286;
        int l = 0; while (l < 5 && k2 >= c_ZB2[l+1]) ++l;
        int L = 2*l + 1, loc = k2 - c_ZB2[l];
        int mi = loc / L, ni = loc % L;
        double beta = PI * (2*j + 1) / 40.0;
        ws[OFF_DM2 + e] = (float)(qwj(10, j) * wigd(F, l, mi - l, ni - l, beta));
    } else if (idx < 96816) {               // Y2B
        int e = idx - 41904; int k2 = e / 192, g = e % 192;
        int l = 0; while (l < 5 && k2 >= c_ZB2[l+1]) ++l;
        int L = 2*l + 1, loc = k2 - c_ZB2[l];
        int m = loc / L - l, n = loc % L - l;
        int bi = g / 64, ai = (g / 8) % 8, ci = g % 8;
        double beta  = (bi + 1) * (PI / 8.0) / 3.0;
        double alpha = 2.0 * PI * ai / 8.0;
        double gamma = (-2.0 * PI + ci * (PI / 2.0)) - alpha;
        double d = wigd(F, l, m, n, beta);
        double ph = -((double)m * alpha + (double)n * gamma);
        ws[OFF_Y2B + 2*e]     = (float)(d * cos(ph));
        ws[OFF_Y2B + 2*e + 1] = (float)(d * sin(ph));
    } else if (idx < 100248) {              // D2R [j][flat], prescaled by (2l+1)
        int e = idx - 96816; int j = e / 286, t = e % 286;
        int l = 0; while (l < 5 && t >= c_ZB2[l+1]) ++l;
        int L = 2*l + 1, loc = t - c_ZB2[l];
        int mi = loc / L, ni = loc % L;
        double beta = PI * (2*j + 1) / 24.0;
        ws[OFF_D2R + e] = (float)((double)L * wigd(F, l, mi - l, ni - l, beta));
    } else if (idx < 100628) {              // T19U [c][n]
        int e = idx - 100248; int c = e / 19, n = e % 19 - 9;
        double ang = 2.0 * PI * (double)(n * c) / 20.0;
        ws[OFF_T19U + 2*e]     = (float)cos(ang);
        ws[OFF_T19U + 2*e + 1] = (float)sin(ang);
    } else if (idx < 100848) {              // T11V [r][c]
        int e = idx - 100628; int r = e / 20, c = e % 20;
        double ang = -2.0 * PI * (double)((r - 5) * c) / 20.0;
        ws[OFF_T11V + 2*e]     = (float)cos(ang);
        ws[OFF_T11V + 2*e + 1] = (float)sin(ang);
    } else if (idx < 100980) {              // T12U [c][n]
        int e = idx - 100848; int c = e / 11, n = e % 11 - 5;
        double ang = 2.0 * PI * (double)(n * c) / 12.0;
        ws[OFF_T12U + 2*e]     = (float)cos(ang);
        ws[OFF_T12U + 2*e + 1] = (float)sin(ang);
    } else if (idx < 102310) {              // TABA (legacy full table)
        int t = idx - 100980;
        int l = 0; while (l < 9 && t >= c_ZB1[l+1]) ++l;
        int L = 2*l + 1, loc = t - c_ZB1[l];
        ((int*)ws)[OFF_TABA + t] = l | ((loc / L) << 8) | ((loc % L) << 16);
    } else if (idx < 102596) {              // TABB
        int t = idx - 102310;
        int l = 0; while (l < 5 && t >= c_ZB2[l+1]) ++l;
        int L = 2*l + 1, loc = t - c_ZB2[l];
        ((int*)ws)[OFF_TABB + t] = l | ((loc / L) << 8) | ((loc % L) << 16);
    } else if (idx < 102796) {              // TH19 [a][mm]
        int e = idx - 102596; int a = e / 10, mm = e % 10;
        double f = (mm == 0) ? 1.0 : 2.0;
        double ang = 2.0 * PI * (double)(mm * a) / 20.0;
        ws[OFF_TH19 + 2*e]     = (float)(f * cos(ang));
        ws[OFF_TH19 + 2*e + 1] = (float)(f * sin(ang));
    } else if (idx < 102868) {              // TH12 [a][mm]
        int e = idx - 102796; int a = e / 6, mm = e % 6;
        double f = (mm == 0) ? 1.0 : 2.0;
        double ang = 2.0 * PI * (double)(mm * a) / 12.0;
        ws[OFF_TH12 + 2*e]     = (float)(f * cos(ang));
        ws[OFF_TH12 + 2*e + 1] = (float)(f * sin(ang));
    } else if (idx < 103014) {              // TABH: 146 half items (l|loc<<8)
        int t = idx - 102868;
        int l = 0, cum = 0, loc = 0;
        for (; l < 6; ++l) {
            int L = 2*l + 1, h = (L*L + 1) / 2;
            if (t < cum + h) { loc = t - cum; break; }
            cum += h;
        }
        ((int*)ws)[OFF_TABH + t] = l | (loc << 8);
    } else {                                // TAH1: 715 upper-half Z items (l|mm<<8|ni<<16)
        int t = idx - 103014;
        int l = 0; while (l < 9 && t >= c_ZBH[l+1]) ++l;
        int L = 2*l + 1, loc = t - c_ZBH[l];
        ((int*)ws)[OFF_TAH1 + t] = l | ((loc / L) << 8) | ((loc % L) << 16);
    }
}

// ---------------- small pipeline kernels ----------------
__global__ void k_dft_alpha(const float* __restrict__ x, const float2* __restrict__ W60,
                            float2* __restrict__ xh) {
    int idx = blockIdx.x * blockDim.x + threadIdx.x;
    if (idx >= BT * 60 * 19) return;
    int r = idx % 19;
    int j = (idx / 19) % 60;
    int b = idx / (19 * 60);
    const float* xr = x + (b * 60 + j) * 60;
    const float2* wr = W60 + r * 60;
    float re = 0.f, im = 0.f;
    for (int a = 0; a < 60; ++a) {
        float v = xr[a];
        float2 w = wr[a];
        re += v * w.x; im += v * w.y;
    }
    xh[idx] = make_float2(re * (1.f / 60.f), im * (1.f / 60.f));
}

__global__ void k_X1(const float2* __restrict__ xh, const float* __restrict__ DM1,
                     float2* __restrict__ X) {
    int idx = blockIdx.x * blockDim.x + threadIdx.x;
    if (idx >= 100 * BT) return;
    int b = idx % BT, k = idx / BT;
    int l = 0; while ((l + 1) * (l + 1) <= k) ++l;
    int r = (k - l*l - l) + 9;
    float re = 0.f, im = 0.f;
    for (int j = 0; j < 60; ++j) {
        float d = DM1[k * 60 + j];
        float2 v = xh[(b * 60 + j) * 19 + r];
        re += d * v.x; im += d * v.y;
    }
    X[k * BT + b] = make_float2(re, im);
}

__global__ void k_Yk1(const float* __restrict__ k1, const float2* __restrict__ Y1B,
                      float2* __restrict__ Yk1) {
    int idx = blockIdx.x * blockDim.x + threadIdx.x;
    if (idx >= 100 * 20) return;
    int o = idx % 20, k = idx / 20;
    float re = 0.f, im = 0.f;
    for (int g = 0; g < 24; ++g) {
        float2 y = Y1B[k * 24 + g];
        float w = k1[o * 24 + g];
        re += y.x * w; im += y.y * w;
    }
    const float SC1 = 0.20412414523193154f;  // 1/sqrt(24)
    Yk1[idx] = make_float2(re * SC1, im * SC1);
}

// Yk2 layout: [o][k2][i]; one block per half-item, mirror written via Hermitian symmetry
__global__ __launch_bounds__(NT) void k_Yk2(const float* __restrict__ k2in,
                                            const float2* __restrict__ Y2B,
                                            const int* __restrict__ gTABH,
                                            float2* __restrict__ Yk2) {
    const int h = blockIdx.x;      // 0..145
    const int tid = threadIdx.x;
    int ph = gTABH[h];
    int l = ph & 255, loc = ph >> 8;
    int L = 2 * l + 1;
    int mi = loc / L, ni = loc % L;
    int k2  = c_ZB2[l] + loc;
    int locm = L * L - 1 - loc;
    int k2m = c_ZB2[l] + locm;
    float par = ((mi + ni) & 1) ? -1.f : 1.f;

    __shared__ __align__(16) float2 sY[192];
    for (int t = tid; t < 192; t += NT) sY[t] = Y2B[k2 * 192 + t];
    __syncthreads();
    const float4* sY4 = (const float4*)sY;
    const float SC2 = 0.016137430609197573f; // 1/sqrt(192*20)
    for (int t = tid; t < 800; t += NT) {
        int o = t / 20, i = t % 20;
        const float4* kp = (const float4*)(k2in + (i * 40 + o) * 192);
        float re = 0.f, im = 0.f;
        #pragma unroll 4
        for (int p = 0; p < 48; ++p) {
            float4 w = kp[p];
            float4 y01 = sY4[2*p], y23 = sY4[2*p + 1];
            re += w.x * y01.x + w.y * y01.z + w.z * y23.x + w.w * y23.z;
            im += w.x * y01.y + w.y * y01.w + w.z * y23.y + w.w * y23.w;
        }
        re *= SC2; im *= SC2;
        Yk2[(o * 286 + k2) * 20 + i] = make_float2(re, im);
        if (k2m != k2)
            Yk2[(o * 286 + k2m) * 20 + i] = make_float2(par * re, -par * im);
    }
}

// ---------------- stage 1: block (b,f1); wave-owned j; Hermitian-halved; bank-aware lane maps ----------------
// X2 layout: [b][k2][f1].  No min-waves hint (R7: forcing VGPR low spilled 58 MB to scratch).
// X2 accumulation via LDS float atomics (saves 10 VGPR vs register array; target <=64 VGPR tier).
__global__ __launch_bounds__(NT) void k_stage1(
    const float2* __restrict__ X, const float2* __restrict__ Yk1,
    const float* __restrict__ gD1R, const float* __restrict__ gDM2,
    const float2* __restrict__ gT19, const float2* __restrict__ gT11,
    const float2* __restrict__ gTH19,
    const int* __restrict__ gTAH1, const int* __restrict__ gTABB,
    float2* __restrict__ X2g) {
    const int b = blockIdx.x % BT;
    const int f = blockIdx.x / BT;   // 0..19
    const int tid = threadIdx.x;
    const int wv = tid >> 6, lane = tid & 63;

    __shared__ __align__(16) float2 sZ[715];     // upper-half rows only (mi >= l)
    __shared__ __align__(16) float2 sX2[286];
    __shared__ __align__(16) float2 sT19[440];   // [c][n], stride 22 (U phase; rows broadcast per c-group)
    __shared__ __align__(16) float2 sTH19[260];  // [a][mm], stride 13 (odd: float2 reads, 2-way max)
    __shared__ __align__(16) float2 sT11[220];   // [r][c], stride 20
    __shared__ __align__(16) float2 sA[4][224];  // per-wave: S(10x22) | x1(400f) | G(66)
    __shared__ __align__(16) float2 sB[4][240];  // per-wave: U(20x12) | V(6x22)

    for (int t = tid; t < 380; t += NT) sT19[(t / 19) * 22 + (t % 19)] = gT19[t];
    for (int t = tid; t < 200; t += NT) sTH19[(t / 10) * 13 + (t % 10)] = gTH19[t];
    for (int t = tid; t < 220; t += NT) sT11[t] = gT11[t];
    for (int t = tid; t < 286; t += NT) sX2[t] = make_float2(0.f, 0.f);
    for (int t = tid; t < 715; t += NT) {
        int p = gTAH1[t];
        int l = p & 255, mm = (p >> 8) & 255, ni = p >> 16;
        float2 a = X[(l*l + l + mm) * BT + b];
        float2 y = Yk1[(l*l + ni) * 20 + f];
        sZ[t] = make_float2(a.x * y.x + a.y * y.y, a.y * y.x - a.x * y.y);
    }
    __syncthreads();

    float2* S   = sA[wv];            // [mm][ni] mm=0..9, stride 22
    float2* U   = sB[wv];            // [c][mm] stride 12
    float*  x1  = (float*)sA[wv];    // [a][c] stride 20 floats
    float2* V   = sB[wv];            // [nn][a] nn=0..5, stride 22
    float2* G   = sA[wv];            // [mm][ni2] mm=0..5, stride 11

    for (int jj = 0; jj < 5; ++jj) {
        const int j = wv + 4 * jj;

        // ---- S[m][n], m=0..9 only (S[-m][-n]=conj(S[m][n])); Z from half store
        {
            const float* dp = gD1R + j * 1330;
            for (int t = lane; t < 190; t += 64) {
                int mm = t / 19, ni = t % 19;
                int n = ni - 9;
                int an = n < 0 ? -n : n;
                int lmin = mm > an ? mm : an;
                float re = 0.f, im = 0.f;
                for (int l = lmin; l < 10; ++l) {
                    int L = 2*l + 1;
                    float dv = dp[c_ZB1[l] + (mm + l) * L + (n + l)];
                    float2 z = sZ[c_ZBH[l] + mm * L + (n + l)];
                    re += dv * z.x; im += dv * z.y;
                }
                S[mm * 22 + ni] = make_float2(re, im);
            }
        }
        wsync();

        // ---- U[m][c] = sum_n S[m][n] T19[c][n], m=0..9; write U[c][m]
        // lane map: mm fastest -> S rows on distinct banks (<=2-way); T19 rows broadcast per c-group
        for (int t = lane; t < 200; t += 64) {
            int mm = t % 10, c = t / 10;
            const float4* sp = (const float4*)(S + mm * 22);
            const float4* tp = (const float4*)(sT19 + c * 22);
            float re = 0.f, im = 0.f;
            #pragma unroll
            for (int p = 0; p < 9; ++p) {
                float4 s = sp[p], w = tp[p];
                re += s.x * w.x - s.y * w.y + s.z * w.z - s.w * w.w;
                im += s.x * w.y + s.y * w.x + s.z * w.w + s.w * w.z;
            }
            float2 s1 = S[mm * 22 + 18], w1 = sT19[c * 22 + 18];
            re += s1.x * w1.x - s1.y * w1.y;
            im += s1.x * w1.y + s1.y * w1.x;
            U[c * 12 + mm] = make_float2(re, im);
        }
        wsync();

        // ---- x1[a][c] = sum_{mm=0..9} Re(U[mm][c] * TH19[a][mm]); relu
        // lane map: a fastest -> TH19 rows (stride 13, odd) <=2-way; U rows broadcast per c-group
        for (int t = lane; t < 400; t += 64) {
            int a = t % 20, c = t / 20;
            const float4* up = (const float4*)(U + c * 12);
            const float2* tp = sTH19 + a * 13;
            float a0 = 0.f, a1 = 0.f;
            #pragma unroll
            for (int p = 0; p < 5; ++p) {
                float4 u = up[p];
                float2 w0 = tp[2*p], w1 = tp[2*p + 1];
                a0 += u.x * w0.x - u.y * w0.y;
                a1 += u.z * w1.x - u.w * w1.y;
            }
            float v = a0 + a1;
            x1[a * 20 + c] = v > 0.f ? v : 0.f;
        }
        wsync();

        // ---- V[nn][a] = sum_c x1[a][c] e^{-2pi i nn c/20}, nn=0..5 (V[-nn]=conj)
        // lane map: nn fastest -> x1 rows distinct banks (<=2-way); T11 rows distinct banks
        for (int t = lane; t < 120; t += 64) {
            int nn = t % 6, a = t / 6;
            const float4* xp = (const float4*)(x1 + a * 20);
            const float4* tp = (const float4*)(sT11 + (nn + 5) * 20);
            float r0 = 0.f, i0 = 0.f, r1 = 0.f, i1 = 0.f;
            #pragma unroll
            for (int p = 0; p < 5; ++p) {
                float4 xv = xp[p];
                float4 t01 = tp[2*p], t23 = tp[2*p + 1];
                r0 += xv.x * t01.x + xv.y * t01.z;
                i0 += xv.x * t01.y + xv.y * t01.w;
                r1 += xv.z * t23.x + xv.w * t23.z;
                i1 += xv.z * t23.y + xv.w * t23.w;
            }
            V[nn * 22 + a] = make_float2(r0 + r1, i0 + i1);
        }
        wsync();

        // ---- G[mm][nn2], mm=0..5, nn2=-5..5; V[-n] = conj(V[n])
        for (int t = lane; t < 66; t += 64) {
            int mm = t / 11, ni2 = t % 11;
            int nn2 = ni2 - 5;
            int na = nn2 < 0 ? -nn2 : nn2;
            float s = nn2 < 0 ? -1.f : 1.f;
            const float4* vp = (const float4*)(V + na * 22);
            const float4* tp = (const float4*)(sT11 + (mm + 5) * 20);
            float r0 = 0.f, i0 = 0.f, r1 = 0.f, i1 = 0.f;
            #pragma unroll
            for (int q = 0; q < 10; ++q) {
                float4 v = vp[q], w = tp[q];
                float vy0 = s * v.y, vy1 = s * v.w;
                r0 += v.x * w.x - vy0 * w.y;
                i0 += v.x * w.y + vy0 * w.x;
                r1 += v.z * w.z - vy1 * w.w;
                i1 += v.z * w.w + vy1 * w.z;
            }
            G[mm * 11 + ni2] = make_float2(r0 + r1, i0 + i1);
        }
        wsync();

        // ---- sX2[k2] += DM2[j][k2] * G (negatives via conj); LDS float atomics
        {
            const float* dmp = gDM2 + j * 286;
            for (int k2 = lane; k2 < 286; k2 += 64) {
                int p = gTABB[k2];
                int l = p & 255, mi = (p >> 8) & 255, ni = p >> 16;
                int m = mi - l, n = ni - l;
                int gi; float sg;
                if (m >= 0) { gi = m * 11 + (n + 5); sg = 1.f; }
                else        { gi = (-m) * 11 + (5 - n); sg = -1.f; }
                float dm = dmp[k2];
                float2 g = G[gi];
                atomicAdd(&sX2[k2].x, dm * g.x);
                atomicAdd(&sX2[k2].y, dm * sg * g.y);
            }
        }
        wsync();
    }
    __syncthreads();

    for (int t = tid; t < 286; t += NT) {
        float2 v = sX2[t];
        X2g[b * 5720 + t * 20 + f] =
            make_float2(v.x * (1.f / 400.f), v.y * (1.f / 400.f));
    }
}

// ---------------- stage 2a: Z half-items + Hermitian mirror ----------------
__global__ __launch_bounds__(NT) void k_Z2(
    const float2* __restrict__ X2g, const float2* __restrict__ Yk2,
    const int* __restrict__ gTABB, const int* __restrict__ gTABH,
    float2* __restrict__ Z2g) {
    const int bt = blockIdx.x & 7;        // 0..7
    const int o  = blockIdx.x >> 3;       // 0..39
    const int b0 = bt * 16;
    const int tid = threadIdx.x;

    __shared__ __align__(16) float2 sB[5792];

    const float2* Bg = Yk2 + o * 5720;
    for (int e = tid; e < 5720; e += NT) {
        int k2 = e / 20, i = e % 20;
        int p = gTABB[k2];
        int l = p & 255, r = (p >> 8) & 255, kk = p >> 16;
        sB[c_BOFF[l] + r * (40 * l + 22) + kk * 20 + i] = Bg[e];
    }
    __syncthreads();

    for (int q = tid; q < 16 * 146; q += NT) {
        int b_local = q / 146, h = q % 146;
        int ph = gTABH[h];
        int l = ph & 255, loc = ph >> 8;
        int L = 2 * l + 1;
        int mi = loc / L, ni = loc % L;
        const float4* ap = (const float4*)(X2g + (size_t)(b0 + b_local) * 5720
                                           + (c_ZB2[l] + mi * L) * 20);
        const float4* bp = (const float4*)(sB + c_BOFF[l] + ni * (40 * l + 22));
        float re = 0.f, im = 0.f;
        int n4 = 10 * L;
        for (int p4 = 0; p4 < n4; ++p4) {
            float4 a = ap[p4], y = bp[p4];
            re += a.x * y.x + a.y * y.y + a.z * y.z + a.w * y.w;
            im += a.y * y.x - a.x * y.y + a.w * y.z - a.z * y.w;
        }
        size_t base = ((size_t)(b0 + b_local) * 40 + o) * 286;
        Z2g[base + c_ZB2[l] + loc] = make_float2(re, im);
        int locm = L * L - 1 - loc;
        if (locm != loc) {
            float sg = ((mi + ni) & 1) ? -1.f : 1.f;
            Z2g[base + c_ZB2[l] + locm] = make_float2(sg * re, -sg * im);
        }
    }
}

// ---------------- stage 2b: Hermitian-halved j-loop + integrate; bank-aware strides ----------------
__global__ __launch_bounds__(NT) void k_stage2b(
    const float2* __restrict__ Z2g, const float* __restrict__ gD2R,
    const float2* __restrict__ gT12, const float2* __restrict__ gTH12,
    const float* __restrict__ gW2J, float* __restrict__ feat) {
    const int b = blockIdx.x % BT;
    const int o = blockIdx.x / BT;   // 0..39
    const int tid = threadIdx.x;
    const int wv = tid >> 6, lane = tid & 63;

    __shared__ __align__(16) float2 sZb[286];
    __shared__ __align__(16) float2 sT12[168];   // [c][n], stride 14
    __shared__ __align__(16) float2 sTH12[120];  // [a][mm], stride 10 (was 8: {0,16} 6-way)
    __shared__ __align__(16) float2 sS[4][88];   // [mm][ni] mm=0..5, stride 14
    __shared__ __align__(16) float2 sU[4][120];  // [c][mm], stride 10
    __shared__ float sredw[4];

    const float2* Zr = Z2g + ((size_t)b * 40 + o) * 286;
    for (int t = tid; t < 286; t += NT) sZb[t] = Zr[t];
    for (int t = tid; t < 132; t += NT) sT12[(t / 11) * 14 + (t % 11)] = gT12[t];
    for (int t = tid; t < 72; t += NT) sTH12[(t / 6) * 10 + (t % 6)] = gTH12[t];
    __syncthreads();

    float2* S = sS[wv];
    float2* U = sU[wv];
    float facc = 0.f;

    for (int jj = 0; jj < 3; ++jj) {
        const int j = wv + 4 * jj;

        // ---- S2[m][n], m=0..5 only
        {
            const float* dp = gD2R + j * 286;
            for (int t = lane; t < 66; t += 64) {
                int mm = t / 11, ni = t % 11;
                int n = ni - 5;
                int an = n < 0 ? -n : n;
                int lmin = mm > an ? mm : an;
                float re = 0.f, im = 0.f;
                for (int l = lmin; l < 6; ++l) {
                    int L = 2*l + 1;
                    int off = c_ZB2[l] + (mm + l) * L + (n + l);
                    float dv = dp[off];
                    float2 z = sZb[off];
                    re += dv * z.x; im += dv * z.y;
                }
                S[mm * 14 + ni] = make_float2(re, im);
            }
        }
        wsync();

        // ---- U2[m][c] = sum_n S2[m][n] T12[c][n], m=0..5; write U[c][m]
        for (int t = lane; t < 72; t += 64) {
            int mm = t % 6, c = t / 6;
            const float4* sp = (const float4*)(S + mm * 14);
            const float4* tp = (const float4*)(sT12 + c * 14);
            float re = 0.f, im = 0.f;
            #pragma unroll
            for (int p = 0; p < 5; ++p) {
                float4 s = sp[p], w = tp[p];
                re += s.x * w.x - s.y * w.y + s.z * w.z - s.w * w.w;
                im += s.x * w.y + s.y * w.x + s.z * w.w + s.w * w.z;
            }
            float2 s1 = S[mm * 14 + 10], w1 = sT12[c * 14 + 10];
            re += s1.x * w1.x - s1.y * w1.y;
            im += s1.x * w1.y + s1.y * w1.x;
            U[c * 10 + mm] = make_float2(re, im);
        }
        wsync();

        // ---- x2[a][c] = sum_{mm=0..5} Re(U2[mm][c]*TH12[a][mm]); relu; integrate
        // lane map: a fastest -> TH12 rows (stride 10) spread; U rows broadcast per c-group
        {
            float wj = gW2J[j];
            for (int t = lane; t < 144; t += 64) {
                int a = t % 12, c = t / 12;
                const float4* up = (const float4*)(U + c * 10);
                const float4* tp = (const float4*)(sTH12 + a * 10);
                float acc = 0.f;
                #pragma unroll
                for (int p = 0; p < 3; ++p) {
                    float4 u = up[p], w = tp[p];
                    acc += u.x * w.x - u.y * w.y + u.z * w.z - u.w * w.w;
                }
                if (acc > 0.f) facc += wj * acc;
            }
        }
        wsync();
    }

    #pragma unroll
    for (int d = 32; d > 0; d >>= 1) facc += __shfl_down(facc, d, 64);
    if (lane == 0) sredw[wv] = facc;
    __syncthreads();
    if (tid == 0) {
        const float INTEG = 0.27415567780803774f;  // (2*pi/12)^2
        feat[b * 40 + o] = (sredw[0] + sredw[1] + sredw[2] + sredw[3]) * INTEG;
    }
}

__global__ void k_out(const float* __restrict__ feat, const float* __restrict__ w,
                      const float* __restrict__ bias, float* __restrict__ out) {
    int idx = blockIdx.x * blockDim.x + threadIdx.x;
    if (idx >= BT * 10) return;
    int fo = idx % 10, b = idx / 10;
    float acc = bias[fo];
    for (int o2 = 0; o2 < 40; ++o2) acc += feat[b * 40 + o2] * w[fo * 40 + o2];
    out[idx] = acc;
}

extern "C" void kernel_launch(void* const* d_in, const int* in_sizes, int n_in,
                              void* d_out, int out_size, void* d_ws, size_t ws_size,
                              hipStream_t stream) {
    (void)in_sizes; (void)n_in; (void)out_size; (void)ws_size;
    const float* x   = (const float*)d_in[0];
    const float* k1  = (const float*)d_in[1];
    const float* k2  = (const float*)d_in[2];
    const float* wO  = (const float*)d_in[3];
    const float* bO  = (const float*)d_in[4];
    float* out = (float*)d_out;

    float* ws = (float*)d_ws;
    const float2* cW60 = (const float2*)(ws + OFF_W60);
    const float*  cW2J = ws + OFF_W2J;
    const float*  cDM1 = ws + OFF_DM1;
    const float2* cY1B = (const float2*)(ws + OFF_Y1B);
    const float*  gD1R = ws + OFF_D1R;
    const float*  gDM2 = ws + OFF_DM2;
    const float2* cY2B = (const float2*)(ws + OFF_Y2B);
    const float*  gD2R = ws + OFF_D2R;
    const float2* gT19 = (const float2*)(ws + OFF_T19U);
    const float2* gT11 = (const float2*)(ws + OFF_T11V);
    const float2* gT12 = (const float2*)(ws + OFF_T12U);
    const float2* gTH19 = (const float2*)(ws + OFF_TH19);
    const float2* gTH12 = (const float2*)(ws + OFF_TH12);
    const int*    gTABB = (const int*)(ws + OFF_TABB);
    const int*    gTABH = (const int*)(ws + OFF_TABH);
    const int*    gTAH1 = (const int*)(ws + OFF_TAH1);

    float2* xh   = (float2*)(ws + OFF_END);          // 128*60*19
    float2* X    = xh + BT * 60 * 19;                // 100*128
    float2* Yk1  = X + 100 * BT;                     // 100*20
    float2* Yk2  = Yk1 + 100 * 20;                   // 40*286*20
    float2* X2   = Yk2 + 40 * 286 * 20;              // 128*286*20  [b][k2][i]
    float*  feat = (float*)(X2 + (size_t)BT * 5720); // 128*40
    float2* Z2   = (float2*)(feat + BT * 40);        // 128*40*286

    k_init<<<(N_INIT + NT - 1) / NT, NT, 0, stream>>>(ws);
    k_dft_alpha<<<(BT * 60 * 19 + NT - 1) / NT, NT, 0, stream>>>(x, cW60, xh);
    k_X1<<<(100 * BT + NT - 1) / NT, NT, 0, stream>>>(xh, cDM1, X);
    k_Yk1<<<(100 * 20 + NT - 1) / NT, NT, 0, stream>>>(k1, cY1B, Yk1);
    k_Yk2<<<146, NT, 0, stream>>>(k2, cY2B, gTABH, Yk2);
    k_stage1<<<BT * 20, NT, 0, stream>>>(X, Yk1, gD1R, gDM2, gT19, gT11, gTH19, gTAH1, gTABB, X2);
    k_Z2<<<320, NT, 0, stream>>>(X2, Yk2, gTABB, gTABH, Z2);
    k_stage2b<<<BT * 40, NT, 0, stream>>>(Z2, gD2R, gT12, gTH12, cW2J, feat);
    k_out<<<(BT * 10 + NT - 1) / NT, NT, 0, stream>>>(feat, wO, bO, out);
}

// Round 10
// 489.221 us; speedup vs baseline: 1.2714x; 1.2714x over previous
//
#include <hip/hip_runtime.h>
#include <cmath>

#define NT 256
#define BT 128

// ---------------- ws float-offsets for constant tables ----------------
#define OFF_W60   0          // 19*60 complex
#define OFF_E20   2280       // legacy
#define OFF_E12   2320       // legacy
#define OFF_W2J   2344       // 12 floats
#define OFF_DM1   2356       // 100*60
#define OFF_Y1B   8356       // 100*24 complex
#define OFF_D1R   13156      // [j=20][flat=1330] (2l+1)*d^l at beta1
#define OFF_DM2   39756      // [j=20][k2=286]  w1[j]*d^l(beta1_j)  (legacy)
#define OFF_Y2B   45476      // 286*192 complex
#define OFF_D2R   155300     // [j=12][flat=286] (2l+1)*d^l at beta2
#define OFF_T19U  158732     // 20x19 complex [c][n] e^{+2pi i n c/20}
#define OFF_T11V  159492     // 11x20 complex [r][c] e^{-2pi i (r-5) c/20}
#define OFF_T12U  159932     // 12x11 complex [c][n] e^{+2pi i n c/12}
#define OFF_TABA  160196     // 1330 int packed (legacy, full Z table)
#define OFF_TABB  161526     // 286 int packed
#define OFF_TH19  161812     // 20x10 complex [a][mm] f*e^{+2pi i mm a/20}, f=1 (mm=0) else 2
#define OFF_TH12  162212     // 12x6 complex [a][mm] f*e^{+2pi i mm a/12}
#define OFF_TABH  162356     // 146 int packed (l | loc<<8): half items per l
#define OFF_TAH1  162504     // 715 int packed (l | mm<<8 | ni<<16): upper-half Z items
#define OFF_DM2T  163220     // [k2=286][j=20] w1[j]*d^l(beta1_j)/400 (transposed, scaled)
#define OFF_TGIX  168940     // 286 int: gi | (sgbit<<16)
#define OFF_END   169228
#define N_INIT    109735

__constant__ int c_ZB1[10] = {0,1,10,35,84,165,286,455,680,969};
__constant__ int c_ZBH[10] = {0,1,7,22,50,95,161,252,372,525};  // upper-half Z offsets, total 715
__constant__ int c_ZB2[6]  = {0,1,10,35,84,165};
__constant__ int c_BOFF[6] = {0,22,208,718,1712,3350};  // padded row offsets for k_Z2 LDS

// wave-local sync: per-wave-private LDS phase buffers only.
__device__ inline void wsync() {
    __asm__ volatile("" ::: "memory");
    __builtin_amdgcn_s_waitcnt(0xC07F);   // vmcnt=63, expcnt=7, lgkmcnt=0
    __builtin_amdgcn_wave_barrier();
    __asm__ volatile("" ::: "memory");
}

// ---------------- fp64 helpers for the init kernel ----------------
__device__ inline double dipow(double x, int e) {
    double r = 1.0;
    for (int i = 0; i < e; ++i) r *= x;
    return r;
}

__device__ double wigd(const double* F, int l, int mp, int m, double beta) {
    double cb = cos(beta * 0.5), sb = sin(beta * 0.5);
    int smin = m - mp; if (smin < 0) smin = 0;
    int smax = l + m;  if (l - mp < smax) smax = l - mp;
    double pref = sqrt(F[l+mp] * F[l-mp] * F[l+m] * F[l-m]);
    double sum = 0.0;
    for (int s = smin; s <= smax; ++s) {
        double t = pref / (F[l+m-s] * F[s] * F[mp-m+s] * F[l-mp-s]);
        t *= dipow(cb, 2*l + m - mp - 2*s) * dipow(sb, mp - m + 2*s);
        sum += ((mp - m + s) & 1) ? -t : t;
    }
    return sum;
}

__device__ double qwj(int bnd, int j) {
    const double PI = 3.14159265358979323846;
    double theta = PI * (2*j + 1) / (4.0 * bnd);
    double s = 0.0;
    for (int k = 0; k < bnd; ++k) s += sin(theta * (2*k + 1)) / (2*k + 1);
    return 2.0 / bnd * sin(theta) * s;
}

// ---------------- init ----------------
__global__ void k_init(float* __restrict__ ws) {
    int idx = blockIdx.x * blockDim.x + threadIdx.x;
    if (idx >= N_INIT) return;
    double F[20];
    F[0] = 1.0;
    #pragma unroll
    for (int i = 1; i < 20; ++i) F[i] = F[i-1] * i;
    const double PI = 3.14159265358979323846;

    if (idx < 1140) {                       // W60
        int r = idx / 60, a = idx % 60;
        double ang = -2.0 * PI * (double)((r - 9) * a) / 60.0;
        ws[OFF_W60 + 2*idx]     = (float)cos(ang);
        ws[OFF_W60 + 2*idx + 1] = (float)sin(ang);
    } else if (idx < 1160) {
        int t = idx - 1140;
        double ang = 2.0 * PI * t / 20.0;
        ws[OFF_E20 + 2*t]     = (float)cos(ang);
        ws[OFF_E20 + 2*t + 1] = (float)sin(ang);
    } else if (idx < 1172) {
        int t = idx - 1160;
        double ang = 2.0 * PI * t / 12.0;
        ws[OFF_E12 + 2*t]     = (float)cos(ang);
        ws[OFF_E12 + 2*t + 1] = (float)sin(ang);
    } else if (idx < 1184) {                // W2J
        int j = idx - 1172;
        ws[OFF_W2J + j] = (float)qwj(6, j);
    } else if (idx < 7184) {                // DM1[k][j]
        int e = idx - 1184; int k = e / 60, j = e % 60;
        int l = 0; while ((l + 1) * (l + 1) <= k) ++l;
        int m = k - l*l - l;
        double beta = PI * (2*j + 1) / 120.0;
        ws[OFF_DM1 + e] = (float)(qwj(30, j) * wigd(F, l, m, 0, beta));
    } else if (idx < 9584) {                // Y1B
        int e = idx - 7184; int k = e / 24, g = e % 24;
        int l = 0; while ((l + 1) * (l + 1) <= k) ++l;
        int m = k - l*l - l;
        int bi = g / 8, ai = g % 8;
        double beta  = (bi + 1) * (PI / 8.0) / 3.0;
        double alpha = 2.0 * PI * ai / 8.0;
        double d = wigd(F, l, m, 0, beta);
        double ph = -(double)m * alpha;
        ws[OFF_Y1B + 2*e]     = (float)(d * cos(ph));
        ws[OFF_Y1B + 2*e + 1] = (float)(d * sin(ph));
    } else if (idx < 36184) {               // D1R [j][flat], prescaled by (2l+1)
        int e = idx - 9584; int j = e / 1330, t = e % 1330;
        int l = 0; while (l < 9 && t >= c_ZB1[l+1]) ++l;
        int L = 2*l + 1, loc = t - c_ZB1[l];
        int mi = loc / L, ni = loc % L;
        double beta = PI * (2*j + 1) / 40.0;
        ws[OFF_D1R + e] = (float)((double)L * wigd(F, l, mi - l, ni - l, beta));
    } else if (idx < 41904) {               // DM2 [j][k2] (legacy)
        int e = idx - 36184; int j = e / 286, k2 = e % 286;
        int l = 0; while (l < 5 && k2 >= c_ZB2[l+1]) ++l;
        int L = 2*l + 1, loc = k2 - c_ZB2[l];
        int mi = loc / L, ni = loc % L;
        double beta = PI * (2*j + 1) / 40.0;
        ws[OFF_DM2 + e] = (float)(qwj(10, j) * wigd(F, l, mi - l, ni - l, beta));
    } else if (idx < 96816) {               // Y2B
        int e = idx - 41904; int k2 = e / 192, g = e % 192;
        int l = 0; while (l < 5 && k2 >= c_ZB2[l+1]) ++l;
        int L = 2*l + 1, loc = k2 - c_ZB2[l];
        int m = loc / L - l, n = loc % L - l;
        int bi = g / 64, ai = (g / 8) % 8, ci = g % 8;
        double beta  = (bi + 1) * (PI / 8.0) / 3.0;
        double alpha = 2.0 * PI * ai / 8.0;
        double gamma = (-2.0 * PI + ci * (PI / 2.0)) - alpha;
        double d = wigd(F, l, m, n, beta);
        double ph = -((double)m * alpha + (double)n * gamma);
        ws[OFF_Y2B + 2*e]     = (float)(d * cos(ph));
        ws[OFF_Y2B + 2*e + 1] = (float)(d * sin(ph));
    } else if (idx < 100248) {              // D2R [j][flat], prescaled by (2l+1)
        int e = idx - 96816; int j = e / 286, t = e % 286;
        int l = 0; while (l < 5 && t >= c_ZB2[l+1]) ++l;
        int L = 2*l + 1, loc = t - c_ZB2[l];
        int mi = loc / L, ni = loc % L;
        double beta = PI * (2*j + 1) / 24.0;
        ws[OFF_D2R + e] = (float)((double)L * wigd(F, l, mi - l, ni - l, beta));
    } else if (idx < 100628) {              // T19U [c][n]
        int e = idx - 100248; int c = e / 19, n = e % 19 - 9;
        double ang = 2.0 * PI * (double)(n * c) / 20.0;
        ws[OFF_T19U + 2*e]     = (float)cos(ang);
        ws[OFF_T19U + 2*e + 1] = (float)sin(ang);
    } else if (idx < 100848) {              // T11V [r][c]
        int e = idx - 100628; int r = e / 20, c = e % 20;
        double ang = -2.0 * PI * (double)((r - 5) * c) / 20.0;
        ws[OFF_T11V + 2*e]     = (float)cos(ang);
        ws[OFF_T11V + 2*e + 1] = (float)sin(ang);
    } else if (idx < 100980) {              // T12U [c][n]
        int e = idx - 100848; int c = e / 11, n = e % 11 - 5;
        double ang = 2.0 * PI * (double)(n * c) / 12.0;
        ws[OFF_T12U + 2*e]     = (float)cos(ang);
        ws[OFF_T12U + 2*e + 1] = (float)sin(ang);
    } else if (idx < 102310) {              // TABA (legacy full table)
        int t = idx - 100980;
        int l = 0; while (l < 9 && t >= c_ZB1[l+1]) ++l;
        int L = 2*l + 1, loc = t - c_ZB1[l];
        ((int*)ws)[OFF_TABA + t] = l | ((loc / L) << 8) | ((loc % L) << 16);
    } else if (idx < 102596) {              // TABB
        int t = idx - 102310;
        int l = 0; while (l < 5 && t >= c_ZB2[l+1]) ++l;
        int L = 2*l + 1, loc = t - c_ZB2[l];
        ((int*)ws)[OFF_TABB + t] = l | ((loc / L) << 8) | ((loc % L) << 16);
    } else if (idx < 102796) {              // TH19 [a][mm]
        int e = idx - 102596; int a = e / 10, mm = e % 10;
        double f = (mm == 0) ? 1.0 : 2.0;
        double ang = 2.0 * PI * (double)(mm * a) / 20.0;
        ws[OFF_TH19 + 2*e]     = (float)(f * cos(ang));
        ws[OFF_TH19 + 2*e + 1] = (float)(f * sin(ang));
    } else if (idx < 102868) {              // TH12 [a][mm]
        int e = idx - 102796; int a = e / 6, mm = e % 6;
        double f = (mm == 0) ? 1.0 : 2.0;
        double ang = 2.0 * PI * (double)(mm * a) / 12.0;
        ws[OFF_TH12 + 2*e]     = (float)(f * cos(ang));
        ws[OFF_TH12 + 2*e + 1] = (float)(f * sin(ang));
    } else if (idx < 103014) {              // TABH: 146 half items (l|loc<<8)
        int t = idx - 102868;
        int l = 0, cum = 0, loc = 0;
        for (; l < 6; ++l) {
            int L = 2*l + 1, h = (L*L + 1) / 2;
            if (t < cum + h) { loc = t - cum; break; }
            cum += h;
        }
        ((int*)ws)[OFF_TABH + t] = l | (loc << 8);
    } else if (idx < 103729) {              // TAH1: 715 upper-half Z items (l|mm<<8|ni<<16)
        int t = idx - 103014;
        int l = 0; while (l < 9 && t >= c_ZBH[l+1]) ++l;
        int L = 2*l + 1, loc = t - c_ZBH[l];
        ((int*)ws)[OFF_TAH1 + t] = l | ((loc / L) << 8) | ((loc % L) << 16);
    } else if (idx < 109449) {              // DM2T [k2][j], scaled by 1/400
        int e = idx - 103729; int k2 = e / 20, j = e % 20;
        int l = 0; while (l < 5 && k2 >= c_ZB2[l+1]) ++l;
        int L = 2*l + 1, loc = k2 - c_ZB2[l];
        int mi = loc / L, ni = loc % L;
        double beta = PI * (2*j + 1) / 40.0;
        ws[OFF_DM2T + e] = (float)(qwj(10, j) * wigd(F, l, mi - l, ni - l, beta) / 400.0);
    } else {                                // TGIX: 286 int, gi | (sgbit<<16)
        int t = idx - 109449;
        int l = 0; while (l < 5 && t >= c_ZB2[l+1]) ++l;
        int L = 2*l + 1, loc = t - c_ZB2[l];
        int m = loc / L - l, n = loc % L - l;
        int gi, sgbit;
        if (m >= 0) { gi = m * 11 + (n + 5); sgbit = 0; }
        else        { gi = (-m) * 11 + (5 - n); sgbit = 1; }
        ((int*)ws)[OFF_TGIX + t] = gi | (sgbit << 16);
    }
}

// ---------------- small pipeline kernels ----------------
__global__ void k_dft_alpha(const float* __restrict__ x, const float2* __restrict__ W60,
                            float2* __restrict__ xh) {
    int idx = blockIdx.x * blockDim.x + threadIdx.x;
    if (idx >= BT * 60 * 19) return;
    int r = idx % 19;
    int j = (idx / 19) % 60;
    int b = idx / (19 * 60);
    const float* xr = x + (b * 60 + j) * 60;
    const float2* wr = W60 + r * 60;
    float re = 0.f, im = 0.f;
    for (int a = 0; a < 60; ++a) {
        float v = xr[a];
        float2 w = wr[a];
        re += v * w.x; im += v * w.y;
    }
    xh[idx] = make_float2(re * (1.f / 60.f), im * (1.f / 60.f));
}

__global__ void k_X1(const float2* __restrict__ xh, const float* __restrict__ DM1,
                     float2* __restrict__ X) {
    int idx = blockIdx.x * blockDim.x + threadIdx.x;
    if (idx >= 100 * BT) return;
    int b = idx % BT, k = idx / BT;
    int l = 0; while ((l + 1) * (l + 1) <= k) ++l;
    int r = (k - l*l - l) + 9;
    float re = 0.f, im = 0.f;
    for (int j = 0; j < 60; ++j) {
        float d = DM1[k * 60 + j];
        float2 v = xh[(b * 60 + j) * 19 + r];
        re += d * v.x; im += d * v.y;
    }
    X[k * BT + b] = make_float2(re, im);
}

__global__ void k_Yk1(const float* __restrict__ k1, const float2* __restrict__ Y1B,
                      float2* __restrict__ Yk1) {
    int idx = blockIdx.x * blockDim.x + threadIdx.x;
    if (idx >= 100 * 20) return;
    int o = idx % 20, k = idx / 20;
    float re = 0.f, im = 0.f;
    for (int g = 0; g < 24; ++g) {
        float2 y = Y1B[k * 24 + g];
        float w = k1[o * 24 + g];
        re += y.x * w; im += y.y * w;
    }
    const float SC1 = 0.20412414523193154f;  // 1/sqrt(24)
    Yk1[idx] = make_float2(re * SC1, im * SC1);
}

// Yk2 layout: [o][k2][i]; one block per half-item, mirror written via Hermitian symmetry
__global__ __launch_bounds__(NT) void k_Yk2(const float* __restrict__ k2in,
                                            const float2* __restrict__ Y2B,
                                            const int* __restrict__ gTABH,
                                            float2* __restrict__ Yk2) {
    const int h = blockIdx.x;      // 0..145
    const int tid = threadIdx.x;
    int ph = gTABH[h];
    int l = ph & 255, loc = ph >> 8;
    int L = 2 * l + 1;
    int mi = loc / L, ni = loc % L;
    int k2  = c_ZB2[l] + loc;
    int locm = L * L - 1 - loc;
    int k2m = c_ZB2[l] + locm;
    float par = ((mi + ni) & 1) ? -1.f : 1.f;

    __shared__ __align__(16) float2 sY[192];
    for (int t = tid; t < 192; t += NT) sY[t] = Y2B[k2 * 192 + t];
    __syncthreads();
    const float4* sY4 = (const float4*)sY;
    const float SC2 = 0.016137430609197573f; // 1/sqrt(192*20)
    for (int t = tid; t < 800; t += NT) {
        int o = t / 20, i = t % 20;
        const float4* kp = (const float4*)(k2in + (i * 40 + o) * 192);
        float re = 0.f, im = 0.f;
        #pragma unroll 4
        for (int p = 0; p < 48; ++p) {
            float4 w = kp[p];
            float4 y01 = sY4[2*p], y23 = sY4[2*p + 1];
            re += w.x * y01.x + w.y * y01.z + w.z * y23.x + w.w * y23.z;
            im += w.x * y01.y + w.y * y01.w + w.z * y23.y + w.w * y23.w;
        }
        re *= SC2; im *= SC2;
        Yk2[(o * 286 + k2) * 20 + i] = make_float2(re, im);
        if (k2m != k2)
            Yk2[(o * 286 + k2m) * 20 + i] = make_float2(par * re, -par * im);
    }
}

// ---------------- stage 1: block (b,f1); wave-owned j; Hermitian-halved; G exported to global ----------------
// No DM2 contraction here (moved to k_X2c) -> no long-lived register state, slim LDS.
__global__ __launch_bounds__(NT) void k_stage1(
    const float2* __restrict__ X, const float2* __restrict__ Yk1,
    const float* __restrict__ gD1R,
    const float2* __restrict__ gT19, const float2* __restrict__ gT11,
    const float2* __restrict__ gTH19,
    const int* __restrict__ gTAH1, float2* __restrict__ Gg) {
    const int b = blockIdx.x % BT;
    const int f = blockIdx.x / BT;   // 0..19
    const int tid = threadIdx.x;
    const int wv = tid >> 6, lane = tid & 63;

    __shared__ __align__(16) float2 sZ[715];     // upper-half rows only (mi >= l)
    __shared__ __align__(16) float2 sT19[440];   // [c][n], stride 22
    __shared__ __align__(16) float2 sTH19[240];  // [a][mm], stride 12
    __shared__ __align__(16) float2 sT11[220];   // [r][c], stride 20
    __shared__ __align__(16) float2 sA[4][224];  // per-wave: S(10x22) | x1(400f)
    __shared__ __align__(16) float2 sB[4][240];  // per-wave: U(20x12) | V(6x22)

    for (int t = tid; t < 380; t += NT) sT19[(t / 19) * 22 + (t % 19)] = gT19[t];
    for (int t = tid; t < 200; t += NT) sTH19[(t / 10) * 12 + (t % 10)] = gTH19[t];
    for (int t = tid; t < 220; t += NT) sT11[t] = gT11[t];
    for (int t = tid; t < 715; t += NT) {
        int p = gTAH1[t];
        int l = p & 255, mm = (p >> 8) & 255, ni = p >> 16;
        float2 a = X[(l*l + l + mm) * BT + b];
        float2 y = Yk1[(l*l + ni) * 20 + f];
        sZ[t] = make_float2(a.x * y.x + a.y * y.y, a.y * y.x - a.x * y.y);
    }
    __syncthreads();

    float2* S   = sA[wv];            // [mm][ni] mm=0..9, stride 22
    float2* U   = sB[wv];            // [c][mm] stride 12
    float*  x1  = (float*)sA[wv];    // [a][c] stride 20 floats
    float2* V   = sB[wv];            // [nn][a] nn=0..5, stride 22

    for (int jj = 0; jj < 5; ++jj) {
        const int j = wv + 4 * jj;

        // ---- S[m][n], m=0..9 only (S[-m][-n]=conj(S[m][n])); Z from half store
        {
            const float* dp = gD1R + j * 1330;
            for (int t = lane; t < 190; t += 64) {
                int mm = t / 19, ni = t % 19;
                int n = ni - 9;
                int an = n < 0 ? -n : n;
                int lmin = mm > an ? mm : an;
                float re = 0.f, im = 0.f;
                for (int l = lmin; l < 10; ++l) {
                    int L = 2*l + 1;
                    float dv = dp[c_ZB1[l] + (mm + l) * L + (n + l)];
                    float2 z = sZ[c_ZBH[l] + mm * L + (n + l)];
                    re += dv * z.x; im += dv * z.y;
                }
                S[mm * 22 + ni] = make_float2(re, im);
            }
        }
        wsync();

        // ---- U[m][c] = sum_n S[m][n] T19[c][n], m=0..9; write U[c][m]
        for (int t = lane; t < 200; t += 64) {
            int mm = t / 20, c = t % 20;
            const float4* sp = (const float4*)(S + mm * 22);
            const float4* tp = (const float4*)(sT19 + c * 22);
            float re = 0.f, im = 0.f;
            #pragma unroll
            for (int p = 0; p < 9; ++p) {
                float4 s = sp[p], w = tp[p];
                re += s.x * w.x - s.y * w.y + s.z * w.z - s.w * w.w;
                im += s.x * w.y + s.y * w.x + s.z * w.w + s.w * w.z;
            }
            float2 s1 = S[mm * 22 + 18], w1 = sT19[c * 22 + 18];
            re += s1.x * w1.x - s1.y * w1.y;
            im += s1.x * w1.y + s1.y * w1.x;
            U[c * 12 + mm] = make_float2(re, im);
        }
        wsync();

        // ---- x1[a][c] = sum_{mm=0..9} Re(U[mm][c] * TH19[a][mm]); relu
        for (int t = lane; t < 400; t += 64) {
            int a = t / 20, c = t % 20;
            const float4* up = (const float4*)(U + c * 12);
            const float4* tp = (const float4*)(sTH19 + a * 12);
            float a0 = 0.f, a1 = 0.f;
            #pragma unroll
            for (int p = 0; p < 5; ++p) {
                float4 u = up[p], w = tp[p];
                a0 += u.x * w.x - u.y * w.y;
                a1 += u.z * w.z - u.w * w.w;
            }
            float v = a0 + a1;
            x1[a * 20 + c] = v > 0.f ? v : 0.f;
        }
        wsync();

        // ---- V[nn][a] = sum_c x1[a][c] e^{-2pi i nn c/20}, nn=0..5 (V[-nn]=conj)
        for (int t = lane; t < 120; t += 64) {
            int nn = t / 20, a = t % 20;
            const float4* xp = (const float4*)(x1 + a * 20);
            const float4* tp = (const float4*)(sT11 + (nn + 5) * 20);
            float r0 = 0.f, i0 = 0.f, r1 = 0.f, i1 = 0.f;
            #pragma unroll
            for (int p = 0; p < 5; ++p) {
                float4 xv = xp[p];
                float4 t01 = tp[2*p], t23 = tp[2*p + 1];
                r0 += xv.x * t01.x + xv.y * t01.z;
                i0 += xv.x * t01.y + xv.y * t01.w;
                r1 += xv.z * t23.x + xv.w * t23.z;
                i1 += xv.z * t23.y + xv.w * t23.w;
            }
            V[nn * 22 + a] = make_float2(r0 + r1, i0 + i1);
        }
        wsync();

        // ---- G[mm][nn2] -> global, mm=0..5, nn2=-5..5; V[-n] = conj(V[n])
        for (int t = lane; t < 66; t += 64) {
            int mm = t / 11, ni2 = t % 11;
            int nn2 = ni2 - 5;
            int na = nn2 < 0 ? -nn2 : nn2;
            float s = nn2 < 0 ? -1.f : 1.f;
            const float4* vp = (const float4*)(V + na * 22);
            const float4* tp = (const float4*)(sT11 + (mm + 5) * 20);
            float r0 = 0.f, i0 = 0.f, r1 = 0.f, i1 = 0.f;
            #pragma unroll
            for (int q = 0; q < 10; ++q) {
                float4 v = vp[q], w = tp[q];
                float vy0 = s * v.y, vy1 = s * v.w;
                r0 += v.x * w.x - vy0 * w.y;
                i0 += v.x * w.y + vy0 * w.x;
                r1 += v.z * w.z - vy1 * w.w;
                i1 += v.z * w.w + vy1 * w.z;
            }
            Gg[((size_t)(b * 20 + f) * 20 + j) * 66 + t] = make_float2(r0 + r1, i0 + i1);
        }
        wsync();
    }
}

// ---------------- X2c: X2[b][k2][f] = sum_j DM2T[k2][j] * herm(G[b][f][j], k2) ----------------
__global__ __launch_bounds__(NT) void k_X2c(
    const float2* __restrict__ Gg, const float* __restrict__ gDM2T,
    const int* __restrict__ gTGIX, float2* __restrict__ X2g) {
    const int b = blockIdx.x % BT;
    const int f = blockIdx.x / BT;   // 0..19
    const int tid = threadIdx.x;
    __shared__ __align__(16) float2 sG[1320];   // [j][66]
    const float2* Gp = Gg + (size_t)(b * 20 + f) * 20 * 66;
    for (int t = tid; t < 1320; t += NT) sG[t] = Gp[t];
    __syncthreads();
    for (int k2 = tid; k2 < 286; k2 += NT) {
        int e = gTGIX[k2];
        int gi = e & 0xFFFF;
        float sg = (e >> 16) ? -1.f : 1.f;
        const float* dm = gDM2T + k2 * 20;
        float re = 0.f, im = 0.f;
        #pragma unroll
        for (int j = 0; j < 20; ++j) {
            float d = dm[j];
            float2 g = sG[j * 66 + gi];
            re += d * g.x; im += d * g.y;
        }
        X2g[b * 5720 + k2 * 20 + f] = make_float2(re, sg * im);
    }
}

// ---------------- stage 2a: Z half-items + Hermitian mirror ----------------
__global__ __launch_bounds__(NT) void k_Z2(
    const float2* __restrict__ X2g, const float2* __restrict__ Yk2,
    const int* __restrict__ gTABB, const int* __restrict__ gTABH,
    float2* __restrict__ Z2g) {
    const int bt = blockIdx.x & 7;        // 0..7
    const int o  = blockIdx.x >> 3;       // 0..39
    const int b0 = bt * 16;
    const int tid = threadIdx.x;

    __shared__ __align__(16) float2 sB[5792];

    const float2* Bg = Yk2 + o * 5720;
    for (int e = tid; e < 5720; e += NT) {
        int k2 = e / 20, i = e % 20;
        int p = gTABB[k2];
        int l = p & 255, r = (p >> 8) & 255, kk = p >> 16;
        sB[c_BOFF[l] + r * (40 * l + 22) + kk * 20 + i] = Bg[e];
    }
    __syncthreads();

    for (int q = tid; q < 16 * 146; q += NT) {
        int b_local = q / 146, h = q % 146;
        int ph = gTABH[h];
        int l = ph & 255, loc = ph >> 8;
        int L = 2 * l + 1;
        int mi = loc / L, ni = loc % L;
        const float4* ap = (const float4*)(X2g + (size_t)(b0 + b_local) * 5720
                                           + (c_ZB2[l] + mi * L) * 20);
        const float4* bp = (const float4*)(sB + c_BOFF[l] + ni * (40 * l + 22));
        float re = 0.f, im = 0.f;
        int n4 = 10 * L;
        for (int p4 = 0; p4 < n4; ++p4) {
            float4 a = ap[p4], y = bp[p4];
            re += a.x * y.x + a.y * y.y + a.z * y.z + a.w * y.w;
            im += a.y * y.x - a.x * y.y + a.w * y.z - a.z * y.w;
        }
        size_t base = ((size_t)(b0 + b_local) * 40 + o) * 286;
        Z2g[base + c_ZB2[l] + loc] = make_float2(re, im);
        int locm = L * L - 1 - loc;
        if (locm != loc) {
            float sg = ((mi + ni) & 1) ? -1.f : 1.f;
            Z2g[base + c_ZB2[l] + locm] = make_float2(sg * re, -sg * im);
        }
    }
}

// ---------------- stage 2b: Hermitian-halved j-loop + integrate ----------------
__global__ __launch_bounds__(NT) void k_stage2b(
    const float2* __restrict__ Z2g, const float* __restrict__ gD2R,
    const float2* __restrict__ gT12, const float2* __restrict__ gTH12,
    const float* __restrict__ gW2J, float* __restrict__ feat) {
    const int b = blockIdx.x % BT;
    const int o = blockIdx.x / BT;   // 0..39
    const int tid = threadIdx.x;
    const int wv = tid >> 6, lane = tid & 63;

    __shared__ __align__(16) float2 sZb[286];
    __shared__ __align__(16) float2 sT12[168];   // [c][n], stride 14
    __shared__ __align__(16) float2 sTH12[96];   // [a][mm], stride 8
    __shared__ __align__(16) float2 sS[4][88];   // [mm][ni] mm=0..5, stride 14
    __shared__ __align__(16) float2 sU[4][96];   // [c][mm], stride 8
    __shared__ float sredw[4];

    const float2* Zr = Z2g + ((size_t)b * 40 + o) * 286;
    for (int t = tid; t < 286; t += NT) sZb[t] = Zr[t];
    for (int t = tid; t < 132; t += NT) sT12[(t / 11) * 14 + (t % 11)] = gT12[t];
    for (int t = tid; t < 72; t += NT) sTH12[(t / 6) * 8 + (t % 6)] = gTH12[t];
    __syncthreads();

    float2* S = sS[wv];
    float2* U = sU[wv];
    float facc = 0.f;

    for (int jj = 0; jj < 3; ++jj) {
        const int j = wv + 4 * jj;

        // ---- S2[m][n], m=0..5 only
        {
            const float* dp = gD2R + j * 286;
            for (int t = lane; t < 66; t += 64) {
                int mm = t / 11, ni = t % 11;
                int n = ni - 5;
                int an = n < 0 ? -n : n;
                int lmin = mm > an ? mm : an;
                float re = 0.f, im = 0.f;
                for (int l = lmin; l < 6; ++l) {
                    int L = 2*l + 1;
                    int off = c_ZB2[l] + (mm + l) * L + (n + l);
                    float dv = dp[off];
                    float2 z = sZb[off];
                    re += dv * z.x; im += dv * z.y;
                }
                S[mm * 14 + ni] = make_float2(re, im);
            }
        }
        wsync();

        // ---- U2[m][c] = sum_n S2[m][n] T12[c][n], m=0..5; write U[c][m]
        for (int t = lane; t < 72; t += 64) {
            int mm = t / 12, c = t % 12;
            const float4* sp = (const float4*)(S + mm * 14);
            const float4* tp = (const float4*)(sT12 + c * 14);
            float re = 0.f, im = 0.f;
            #pragma unroll
            for (int p = 0; p < 5; ++p) {
                float4 s = sp[p], w = tp[p];
                re += s.x * w.x - s.y * w.y + s.z * w.z - s.w * w.w;
                im += s.x * w.y + s.y * w.x + s.z * w.w + s.w * w.z;
            }
            float2 s1 = S[mm * 14 + 10], w1 = sT12[c * 14 + 10];
            re += s1.x * w1.x - s1.y * w1.y;
            im += s1.x * w1.y + s1.y * w1.x;
            U[c * 8 + mm] = make_float2(re, im);
        }
        wsync();

        // ---- x2[a][c] = sum_{mm=0..5} Re(U2[mm][c]*TH12[a][mm]); relu; integrate
        {
            float wj = gW2J[j];
            for (int t = lane; t < 144; t += 64) {
                int a = t / 12, c = t % 12;
                const float4* up = (const float4*)(U + c * 8);
                const float4* tp = (const float4*)(sTH12 + a * 8);
                float acc = 0.f;
                #pragma unroll
                for (int p = 0; p < 3; ++p) {
                    float4 u = up[p], w = tp[p];
                    acc += u.x * w.x - u.y * w.y + u.z * w.z - u.w * w.w;
                }
                if (acc > 0.f) facc += wj * acc;
            }
        }
        wsync();
    }

    #pragma unroll
    for (int d = 32; d > 0; d >>= 1) facc += __shfl_down(facc, d, 64);
    if (lane == 0) sredw[wv] = facc;
    __syncthreads();
    if (tid == 0) {
        const float INTEG = 0.27415567780803774f;  // (2*pi/12)^2
        feat[b * 40 + o] = (sredw[0] + sredw[1] + sredw[2] + sredw[3]) * INTEG;
    }
}

__global__ void k_out(const float* __restrict__ feat, const float* __restrict__ w,
                      const float* __restrict__ bias, float* __restrict__ out) {
    int idx = blockIdx.x * blockDim.x + threadIdx.x;
    if (idx >= BT * 10) return;
    int fo = idx % 10, b = idx / 10;
    float acc = bias[fo];
    for (int o2 = 0; o2 < 40; ++o2) acc += feat[b * 40 + o2] * w[fo * 40 + o2];
    out[idx] = acc;
}

extern "C" void kernel_launch(void* const* d_in, const int* in_sizes, int n_in,
                              void* d_out, int out_size, void* d_ws, size_t ws_size,
                              hipStream_t stream) {
    (void)in_sizes; (void)n_in; (void)out_size; (void)ws_size;
    const float* x   = (const float*)d_in[0];
    const float* k1  = (const float*)d_in[1];
    const float* k2  = (const float*)d_in[2];
    const float* wO  = (const float*)d_in[3];
    const float* bO  = (const float*)d_in[4];
    float* out = (float*)d_out;

    float* ws = (float*)d_ws;
    const float2* cW60 = (const float2*)(ws + OFF_W60);
    const float*  cW2J = ws + OFF_W2J;
    const float*  cDM1 = ws + OFF_DM1;
    const float2* cY1B = (const float2*)(ws + OFF_Y1B);
    const float*  gD1R = ws + OFF_D1R;
    const float2* cY2B = (const float2*)(ws + OFF_Y2B);
    const float*  gD2R = ws + OFF_D2R;
    const float2* gT19 = (const float2*)(ws + OFF_T19U);
    const float2* gT11 = (const float2*)(ws + OFF_T11V);
    const float2* gT12 = (const float2*)(ws + OFF_T12U);
    const float2* gTH19 = (const float2*)(ws + OFF_TH19);
    const float2* gTH12 = (const float2*)(ws + OFF_TH12);
    const int*    gTABB = (const int*)(ws + OFF_TABB);
    const int*    gTABH = (const int*)(ws + OFF_TABH);
    const int*    gTAH1 = (const int*)(ws + OFF_TAH1);
    const float*  gDM2T = ws + OFF_DM2T;
    const int*    gTGIX = (const int*)(ws + OFF_TGIX);

    float2* xh   = (float2*)(ws + OFF_END);          // 128*60*19
    float2* X    = xh + BT * 60 * 19;                // 100*128
    float2* Yk1  = X + 100 * BT;                     // 100*20
    float2* Yk2  = Yk1 + 100 * 20;                   // 40*286*20
    float2* X2   = Yk2 + 40 * 286 * 20;              // 128*286*20  [b][k2][i]
    float*  feat = (float*)(X2 + (size_t)BT * 5720); // 128*40
    // Gg (2560*20*66 f2 = 3.38M f2) and Z2 (128*40*286 f2 = 1.46M f2) have disjoint
    // lifetimes: Gg live [stage1, X2c]; Z2 live [Z2, stage2b]. Alias the region.
    float2* Gg   = (float2*)(feat + BT * 40);
    float2* Z2   = Gg;

    k_init<<<(N_INIT + NT - 1) / NT, NT, 0, stream>>>(ws);
    k_dft_alpha<<<(BT * 60 * 19 + NT - 1) / NT, NT, 0, stream>>>(x, cW60, xh);
    k_X1<<<(100 * BT + NT - 1) / NT, NT, 0, stream>>>(xh, cDM1, X);
    k_Yk1<<<(100 * 20 + NT - 1) / NT, NT, 0, stream>>>(k1, cY1B, Yk1);
    k_Yk2<<<146, NT, 0, stream>>>(k2, cY2B, gTABH, Yk2);
    k_stage1<<<BT * 20, NT, 0, stream>>>(X, Yk1, gD1R, gT19, gT11, gTH19, gTAH1, Gg);
    k_X2c<<<BT * 20, NT, 0, stream>>>(Gg, gDM2T, gTGIX, X2);
    k_Z2<<<320, NT, 0, stream>>>(X2, Yk2, gTABB, gTABH, Z2);
    k_stage2b<<<BT * 40, NT, 0, stream>>>(Z2, gD2R, gT12, gTH12, cW2J, feat);
    k_out<<<(BT * 10 + NT - 1) / NT, NT, 0, stream>>>(feat, wO, bO, out);
}

// Round 11
// 437.909 us; speedup vs baseline: 1.4203x; 1.1172x over previous
//
#include <hip/hip_runtime.h>
#include <cmath>

#define NT 256
#define BT 128

// ---------------- ws float-offsets for constant tables ----------------
#define OFF_W60   0          // 19*60 complex
#define OFF_E20   2280       // legacy
#define OFF_E12   2320       // legacy
#define OFF_W2J   2344       // 12 floats
#define OFF_DM1   2356       // 100*60
#define OFF_Y1B   8356       // 100*24 complex
#define OFF_D1R   13156      // [j=20][flat=1330] (2l+1)*d^l at beta1
#define OFF_DM2   39756      // [j=20][k2=286]  w1[j]*d^l(beta1_j)  (legacy)
#define OFF_Y2B   45476      // 286*192 complex
#define OFF_D2R   155300     // [j=12][flat=286] (2l+1)*d^l at beta2
#define OFF_T19U  158732     // 20x19 complex [c][n] e^{+2pi i n c/20}
#define OFF_T11V  159492     // 11x20 complex [r][c] e^{-2pi i (r-5) c/20}
#define OFF_T12U  159932     // 12x11 complex [c][n] e^{+2pi i n c/12}
#define OFF_TABA  160196     // 1330 int packed (legacy, full Z table)
#define OFF_TABB  161526     // 286 int packed
#define OFF_TH19  161812     // 20x10 complex [a][mm] f*e^{+2pi i mm a/20}, f=1 (mm=0) else 2
#define OFF_TH12  162212     // 12x6 complex [a][mm] f*e^{+2pi i mm a/12}
#define OFF_TABH  162356     // 146 int packed (l | loc<<8): half items per l
#define OFF_TAH1  162504     // 715 int packed (l | mm<<8 | ni<<16): upper-half Z items
#define OFF_DM2T  163220     // [k2=286][j=20] w1[j]*d^l(beta1_j)/400 (transposed, scaled)
#define OFF_TGIX  168940     // 286 int: gi | (sgbit<<16)
#define OFF_END   169228
#define N_INIT    109735

__constant__ int c_ZB1[10] = {0,1,10,35,84,165,286,455,680,969};
__constant__ int c_ZBH[10] = {0,1,7,22,50,95,161,252,372,525};  // upper-half Z offsets, total 715
__constant__ int c_ZB2[6]  = {0,1,10,35,84,165};
__constant__ int c_BOFF[6] = {0,22,208,718,1712,3350};  // padded row offsets for k_Z2 LDS

// wave-local sync: per-wave-private LDS phase buffers only.
__device__ inline void wsync() {
    __asm__ volatile("" ::: "memory");
    __builtin_amdgcn_s_waitcnt(0xC07F);   // vmcnt=63, expcnt=7, lgkmcnt=0
    __builtin_amdgcn_wave_barrier();
    __asm__ volatile("" ::: "memory");
}

// ---------------- fp64 helpers for the init kernel ----------------
__device__ inline double dipow(double x, int e) {
    double r = 1.0;
    for (int i = 0; i < e; ++i) r *= x;
    return r;
}

// multiply-by-inverse-factorial form (no per-term fp64 divide) — verified R5, absmax 0.0
__device__ double wigd(const double* F, const double* Fi, int l, int mp, int m, double beta) {
    double cb = cos(beta * 0.5), sb = sin(beta * 0.5);
    int smin = m - mp; if (smin < 0) smin = 0;
    int smax = l + m;  if (l - mp < smax) smax = l - mp;
    double pref = sqrt(F[l+mp] * F[l-mp] * F[l+m] * F[l-m]);
    double sum = 0.0;
    for (int s = smin; s <= smax; ++s) {
        double t = pref * (Fi[l+m-s] * Fi[s] * Fi[mp-m+s] * Fi[l-mp-s]);
        t *= dipow(cb, 2*l + m - mp - 2*s) * dipow(sb, mp - m + 2*s);
        sum += ((mp - m + s) & 1) ? -t : t;
    }
    return sum;
}

__device__ double qwj(int bnd, int j) {
    const double PI = 3.14159265358979323846;
    double theta = PI * (2*j + 1) / (4.0 * bnd);
    double s = 0.0;
    for (int k = 0; k < bnd; ++k) s += sin(theta * (2*k + 1)) / (2*k + 1);
    return 2.0 / bnd * sin(theta) * s;
}

// ---------------- init ----------------
__global__ void k_init(float* __restrict__ ws) {
    int idx = blockIdx.x * blockDim.x + threadIdx.x;
    if (idx >= N_INIT) return;
    double F[20], Fi[20];
    F[0] = 1.0;
    #pragma unroll
    for (int i = 1; i < 20; ++i) F[i] = F[i-1] * i;
    Fi[19] = 1.0 / F[19];
    #pragma unroll
    for (int i = 18; i >= 0; --i) Fi[i] = Fi[i+1] * (i+1);
    const double PI = 3.14159265358979323846;

    if (idx < 1140) {                       // W60
        int r = idx / 60, a = idx % 60;
        double ang = -2.0 * PI * (double)((r - 9) * a) / 60.0;
        ws[OFF_W60 + 2*idx]     = (float)cos(ang);
        ws[OFF_W60 + 2*idx + 1] = (float)sin(ang);
    } else if (idx < 1160) {
        int t = idx - 1140;
        double ang = 2.0 * PI * t / 20.0;
        ws[OFF_E20 + 2*t]     = (float)cos(ang);
        ws[OFF_E20 + 2*t + 1] = (float)sin(ang);
    } else if (idx < 1172) {
        int t = idx - 1160;
        double ang = 2.0 * PI * t / 12.0;
        ws[OFF_E12 + 2*t]     = (float)cos(ang);
        ws[OFF_E12 + 2*t + 1] = (float)sin(ang);
    } else if (idx < 1184) {                // W2J
        int j = idx - 1172;
        ws[OFF_W2J + j] = (float)qwj(6, j);
    } else if (idx < 7184) {                // DM1[k][j]
        int e = idx - 1184; int k = e / 60, j = e % 60;
        int l = 0; while ((l + 1) * (l + 1) <= k) ++l;
        int m = k - l*l - l;
        double beta = PI * (2*j + 1) / 120.0;
        ws[OFF_DM1 + e] = (float)(qwj(30, j) * wigd(F, Fi, l, m, 0, beta));
    } else if (idx < 9584) {                // Y1B
        int e = idx - 7184; int k = e / 24, g = e % 24;
        int l = 0; while ((l + 1) * (l + 1) <= k) ++l;
        int m = k - l*l - l;
        int bi = g / 8, ai = g % 8;
        double beta  = (bi + 1) * (PI / 8.0) / 3.0;
        double alpha = 2.0 * PI * ai / 8.0;
        double d = wigd(F, Fi, l, m, 0, beta);
        double ph = -(double)m * alpha;
        ws[OFF_Y1B + 2*e]     = (float)(d * cos(ph));
        ws[OFF_Y1B + 2*e + 1] = (float)(d * sin(ph));
    } else if (idx < 36184) {               // D1R [j][flat], prescaled by (2l+1)
        int e = idx - 9584; int j = e / 1330, t = e % 1330;
        int l = 0; while (l < 9 && t >= c_ZB1[l+1]) ++l;
        int L = 2*l + 1, loc = t - c_ZB1[l];
        int mi = loc / L, ni = loc % L;
        double beta = PI * (2*j + 1) / 40.0;
        ws[OFF_D1R + e] = (float)((double)L * wigd(F, Fi, l, mi - l, ni - l, beta));
    } else if (idx < 41904) {               // DM2 [j][k2] (legacy)
        int e = idx - 36184; int j = e / 286, k2 = e % 286;
        int l = 0; while (l < 5 && k2 >= c_ZB2[l+1]) ++l;
        int L = 2*l + 1, loc = k2 - c_ZB2[l];
        int mi = loc / L, ni = loc % L;
        double beta = PI * (2*j + 1) / 40.0;
        ws[OFF_DM2 + e] = (float)(qwj(10, j) * wigd(F, Fi, l, mi - l, ni - l, beta));
    } else if (idx < 96816) {               // Y2B
        int e = idx - 41904; int k2 = e / 192, g = e % 192;
        int l = 0; while (l < 5 && k2 >= c_ZB2[l+1]) ++l;
        int L = 2*l + 1, loc = k2 - c_ZB2[l];
        int m = loc / L - l, n = loc % L - l;
        int bi = g / 64, ai = (g / 8) % 8, ci = g % 8;
        double beta  = (bi + 1) * (PI / 8.0) / 3.0;
        double alpha = 2.0 * PI * ai / 8.0;
        double gamma = (-2.0 * PI + ci * (PI / 2.0)) - alpha;
        double d = wigd(F, Fi, l, m, n, beta);
        double ph = -((double)m * alpha + (double)n * gamma);
        ws[OFF_Y2B + 2*e]     = (float)(d * cos(ph));
        ws[OFF_Y2B + 2*e + 1] = (float)(d * sin(ph));
    } else if (idx < 100248) {              // D2R [j][flat], prescaled by (2l+1)
        int e = idx - 96816; int j = e / 286, t = e % 286;
        int l = 0; while (l < 5 && t >= c_ZB2[l+1]) ++l;
        int L = 2*l + 1, loc = t - c_ZB2[l];
        int mi = loc / L, ni = loc % L;
        double beta = PI * (2*j + 1) / 24.0;
        ws[OFF_D2R + e] = (float)((double)L * wigd(F, Fi, l, mi - l, ni - l, beta));
    } else if (idx < 100628) {              // T19U [c][n]
        int e = idx - 100248; int c = e / 19, n = e % 19 - 9;
        double ang = 2.0 * PI * (double)(n * c) / 20.0;
        ws[OFF_T19U + 2*e]     = (float)cos(ang);
        ws[OFF_T19U + 2*e + 1] = (float)sin(ang);
    } else if (idx < 100848) {              // T11V [r][c]
        int e = idx - 100628; int r = e / 20, c = e % 20;
        double ang = -2.0 * PI * (double)((r - 5) * c) / 20.0;
        ws[OFF_T11V + 2*e]     = (float)cos(ang);
        ws[OFF_T11V + 2*e + 1] = (float)sin(ang);
    } else if (idx < 100980) {              // T12U [c][n]
        int e = idx - 100848; int c = e / 11, n = e % 11 - 5;
        double ang = 2.0 * PI * (double)(n * c) / 12.0;
        ws[OFF_T12U + 2*e]     = (float)cos(ang);
        ws[OFF_T12U + 2*e + 1] = (float)sin(ang);
    } else if (idx < 102310) {              // TABA (legacy full table)
        int t = idx - 100980;
        int l = 0; while (l < 9 && t >= c_ZB1[l+1]) ++l;
        int L = 2*l + 1, loc = t - c_ZB1[l];
        ((int*)ws)[OFF_TABA + t] = l | ((loc / L) << 8) | ((loc % L) << 16);
    } else if (idx < 102596) {              // TABB
        int t = idx - 102310;
        int l = 0; while (l < 5 && t >= c_ZB2[l+1]) ++l;
        int L = 2*l + 1, loc = t - c_ZB2[l];
        ((int*)ws)[OFF_TABB + t] = l | ((loc / L) << 8) | ((loc % L) << 16);
    } else if (idx < 102796) {              // TH19 [a][mm]
        int e = idx - 102596; int a = e / 10, mm = e % 10;
        double f = (mm == 0) ? 1.0 : 2.0;
        double ang = 2.0 * PI * (double)(mm * a) / 20.0;
        ws[OFF_TH19 + 2*e]     = (float)(f * cos(ang));
        ws[OFF_TH19 + 2*e + 1] = (float)(f * sin(ang));
    } else if (idx < 102868) {              // TH12 [a][mm]
        int e = idx - 102796; int a = e / 6, mm = e % 6;
        double f = (mm == 0) ? 1.0 : 2.0;
        double ang = 2.0 * PI * (double)(mm * a) / 12.0;
        ws[OFF_TH12 + 2*e]     = (float)(f * cos(ang));
        ws[OFF_TH12 + 2*e + 1] = (float)(f * sin(ang));
    } else if (idx < 103014) {              // TABH: 146 half items (l|loc<<8)
        int t = idx - 102868;
        int l = 0, cum = 0, loc = 0;
        for (; l < 6; ++l) {
            int L = 2*l + 1, h = (L*L + 1) / 2;
            if (t < cum + h) { loc = t - cum; break; }
            cum += h;
        }
        ((int*)ws)[OFF_TABH + t] = l | (loc << 8);
    } else if (idx < 103729) {              // TAH1: 715 upper-half Z items (l|mm<<8|ni<<16)
        int t = idx - 103014;
        int l = 0; while (l < 9 && t >= c_ZBH[l+1]) ++l;
        int L = 2*l + 1, loc = t - c_ZBH[l];
        ((int*)ws)[OFF_TAH1 + t] = l | ((loc / L) << 8) | ((loc % L) << 16);
    } else if (idx < 109449) {              // DM2T [k2][j], scaled by 1/400
        int e = idx - 103729; int k2 = e / 20, j = e % 20;
        int l = 0; while (l < 5 && k2 >= c_ZB2[l+1]) ++l;
        int L = 2*l + 1, loc = k2 - c_ZB2[l];
        int mi = loc / L, ni = loc % L;
        double beta = PI * (2*j + 1) / 40.0;
        ws[OFF_DM2T + e] = (float)(qwj(10, j) * wigd(F, Fi, l, mi - l, ni - l, beta) / 400.0);
    } else {                                // TGIX: 286 int, gi | (sgbit<<16)
        int t = idx - 109449;
        int l = 0; while (l < 5 && t >= c_ZB2[l+1]) ++l;
        int L = 2*l + 1, loc = t - c_ZB2[l];
        int m = loc / L - l, n = loc % L - l;
        int gi, sgbit;
        if (m >= 0) { gi = m * 11 + (n + 5); sgbit = 0; }
        else        { gi = (-m) * 11 + (5 - n); sgbit = 1; }
        ((int*)ws)[OFF_TGIX + t] = gi | (sgbit << 16);
    }
}

// ---------------- small pipeline kernels ----------------
__global__ void k_dft_alpha(const float* __restrict__ x, const float2* __restrict__ W60,
                            float2* __restrict__ xh) {
    int idx = blockIdx.x * blockDim.x + threadIdx.x;
    if (idx >= BT * 60 * 19) return;
    int r = idx % 19;
    int j = (idx / 19) % 60;
    int b = idx / (19 * 60);
    const float* xr = x + (b * 60 + j) * 60;
    const float2* wr = W60 + r * 60;
    float re = 0.f, im = 0.f;
    for (int a = 0; a < 60; ++a) {
        float v = xr[a];
        float2 w = wr[a];
        re += v * w.x; im += v * w.y;
    }
    xh[idx] = make_float2(re * (1.f / 60.f), im * (1.f / 60.f));
}

__global__ void k_X1(const float2* __restrict__ xh, const float* __restrict__ DM1,
                     float2* __restrict__ X) {
    int idx = blockIdx.x * blockDim.x + threadIdx.x;
    if (idx >= 100 * BT) return;
    int b = idx % BT, k = idx / BT;
    int l = 0; while ((l + 1) * (l + 1) <= k) ++l;
    int r = (k - l*l - l) + 9;
    float re = 0.f, im = 0.f;
    for (int j = 0; j < 60; ++j) {
        float d = DM1[k * 60 + j];
        float2 v = xh[(b * 60 + j) * 19 + r];
        re += d * v.x; im += d * v.y;
    }
    X[k * BT + b] = make_float2(re, im);
}

__global__ void k_Yk1(const float* __restrict__ k1, const float2* __restrict__ Y1B,
                      float2* __restrict__ Yk1) {
    int idx = blockIdx.x * blockDim.x + threadIdx.x;
    if (idx >= 100 * 20) return;
    int o = idx % 20, k = idx / 20;
    float re = 0.f, im = 0.f;
    for (int g = 0; g < 24; ++g) {
        float2 y = Y1B[k * 24 + g];
        float w = k1[o * 24 + g];
        re += y.x * w; im += y.y * w;
    }
    const float SC1 = 0.20412414523193154f;  // 1/sqrt(24)
    Yk1[idx] = make_float2(re * SC1, im * SC1);
}

// Yk2 layout: [o][k2][i]; grid 292 = 146 half-items x 2 item-halves (load balance on 256 CUs)
__global__ __launch_bounds__(NT) void k_Yk2(const float* __restrict__ k2in,
                                            const float2* __restrict__ Y2B,
                                            const int* __restrict__ gTABH,
                                            float2* __restrict__ Yk2) {
    const int h = blockIdx.x >> 1;     // 0..145
    const int half = blockIdx.x & 1;   // item-range half
    const int tid = threadIdx.x;
    int ph = gTABH[h];
    int l = ph & 255, loc = ph >> 8;
    int L = 2 * l + 1;
    int mi = loc / L, ni = loc % L;
    int k2  = c_ZB2[l] + loc;
    int locm = L * L - 1 - loc;
    int k2m = c_ZB2[l] + locm;
    float par = ((mi + ni) & 1) ? -1.f : 1.f;

    __shared__ __align__(16) float2 sY[192];
    for (int t = tid; t < 192; t += NT) sY[t] = Y2B[k2 * 192 + t];
    __syncthreads();
    const float4* sY4 = (const float4*)sY;
    const float SC2 = 0.016137430609197573f; // 1/sqrt(192*20)
    for (int t = half * 400 + tid; t < half * 400 + 400; t += NT) {
        int o = t / 20, i = t % 20;
        const float4* kp = (const float4*)(k2in + (i * 40 + o) * 192);
        float re = 0.f, im = 0.f;
        #pragma unroll 4
        for (int p = 0; p < 48; ++p) {
            float4 w = kp[p];
            float4 y01 = sY4[2*p], y23 = sY4[2*p + 1];
            re += w.x * y01.x + w.y * y01.z + w.z * y23.x + w.w * y23.z;
            im += w.x * y01.y + w.y * y01.w + w.z * y23.y + w.w * y23.w;
        }
        re *= SC2; im *= SC2;
        Yk2[(o * 286 + k2) * 20 + i] = make_float2(re, im);
        if (k2m != k2)
            Yk2[(o * 286 + k2m) * 20 + i] = make_float2(par * re, -par * im);
    }
}

// ---------------- stage 1: block (b,f1); wave-owned j; Hermitian-halved; G exported to global ----------------
// U/TH19 stride 14 (8-bank spread, 16B aligned); x1 phase 2x1 c-blocked.
__global__ __launch_bounds__(NT) void k_stage1(
    const float2* __restrict__ X, const float2* __restrict__ Yk1,
    const float* __restrict__ gD1R,
    const float2* __restrict__ gT19, const float2* __restrict__ gT11,
    const float2* __restrict__ gTH19,
    const int* __restrict__ gTAH1, float2* __restrict__ Gg) {
    const int b = blockIdx.x % BT;
    const int f = blockIdx.x / BT;   // 0..19
    const int tid = threadIdx.x;
    const int wv = tid >> 6, lane = tid & 63;

    __shared__ __align__(16) float2 sZ[715];     // upper-half rows only (mi >= l)
    __shared__ __align__(16) float2 sT19[440];   // [c][n], stride 22
    __shared__ __align__(16) float2 sTH19[280];  // [a][mm], stride 14
    __shared__ __align__(16) float2 sT11[220];   // [r][c], stride 20
    __shared__ __align__(16) float2 sA[4][224];  // per-wave: S(10x22) | x1(400f)
    __shared__ __align__(16) float2 sB[4][280];  // per-wave: U(20x14) | V(6x22)

    for (int t = tid; t < 380; t += NT) sT19[(t / 19) * 22 + (t % 19)] = gT19[t];
    for (int t = tid; t < 200; t += NT) sTH19[(t / 10) * 14 + (t % 10)] = gTH19[t];
    for (int t = tid; t < 220; t += NT) sT11[t] = gT11[t];
    for (int t = tid; t < 715; t += NT) {
        int p = gTAH1[t];
        int l = p & 255, mm = (p >> 8) & 255, ni = p >> 16;
        float2 a = X[(l*l + l + mm) * BT + b];
        float2 y = Yk1[(l*l + ni) * 20 + f];
        sZ[t] = make_float2(a.x * y.x + a.y * y.y, a.y * y.x - a.x * y.y);
    }
    __syncthreads();

    float2* S   = sA[wv];            // [mm][ni] mm=0..9, stride 22
    float2* U   = sB[wv];            // [c][mm] stride 14
    float*  x1  = (float*)sA[wv];    // [a][c] stride 20 floats
    float2* V   = sB[wv];            // [nn][a] nn=0..5, stride 22

    for (int jj = 0; jj < 5; ++jj) {
        const int j = wv + 4 * jj;

        // ---- S[m][n], m=0..9 only (S[-m][-n]=conj(S[m][n])); Z from half store
        {
            const float* dp = gD1R + j * 1330;
            for (int t = lane; t < 190; t += 64) {
                int mm = t / 19, ni = t % 19;
                int n = ni - 9;
                int an = n < 0 ? -n : n;
                int lmin = mm > an ? mm : an;
                float re = 0.f, im = 0.f;
                for (int l = lmin; l < 10; ++l) {
                    int L = 2*l + 1;
                    float dv = dp[c_ZB1[l] + (mm + l) * L + (n + l)];
                    float2 z = sZ[c_ZBH[l] + mm * L + (n + l)];
                    re += dv * z.x; im += dv * z.y;
                }
                S[mm * 22 + ni] = make_float2(re, im);
            }
        }
        wsync();

        // ---- U[m][c] = sum_n S[m][n] T19[c][n], m=0..9; write U[c][m] (stride 14)
        for (int t = lane; t < 200; t += 64) {
            int mm = t / 20, c = t % 20;
            const float4* sp = (const float4*)(S + mm * 22);
            const float4* tp = (const float4*)(sT19 + c * 22);
            float re = 0.f, im = 0.f;
            #pragma unroll
            for (int p = 0; p < 9; ++p) {
                float4 s = sp[p], w = tp[p];
                re += s.x * w.x - s.y * w.y + s.z * w.z - s.w * w.w;
                im += s.x * w.y + s.y * w.x + s.z * w.w + s.w * w.z;
            }
            float2 s1 = S[mm * 22 + 18], w1 = sT19[c * 22 + 18];
            re += s1.x * w1.x - s1.y * w1.y;
            im += s1.x * w1.y + s1.y * w1.x;
            U[c * 14 + mm] = make_float2(re, im);
        }
        wsync();

        // ---- x1[a][c],x1[a][c+10] = relu(sum_mm Re(U[mm][c]*TH19[a][mm])); 2x1 c-blocked
        for (int t = lane; t < 200; t += 64) {
            int cp = t % 10, a = t / 10;
            const float4* u0 = (const float4*)(U + cp * 14);
            const float4* u1 = (const float4*)(U + (cp + 10) * 14);
            const float4* tp = (const float4*)(sTH19 + a * 14);
            float s0a = 0.f, s0b = 0.f, s1a = 0.f, s1b = 0.f;
            #pragma unroll
            for (int p = 0; p < 5; ++p) {
                float4 w = tp[p];
                float4 ua = u0[p], ub = u1[p];
                s0a += ua.x * w.x - ua.y * w.y;
                s0b += ua.z * w.z - ua.w * w.w;
                s1a += ub.x * w.x - ub.y * w.y;
                s1b += ub.z * w.z - ub.w * w.w;
            }
            float v0 = s0a + s0b, v1 = s1a + s1b;
            x1[a * 20 + cp]      = v0 > 0.f ? v0 : 0.f;
            x1[a * 20 + cp + 10] = v1 > 0.f ? v1 : 0.f;
        }
        wsync();

        // ---- V[nn][a] = sum_c x1[a][c] e^{-2pi i nn c/20}, nn=0..5 (V[-nn]=conj)
        for (int t = lane; t < 120; t += 64) {
            int nn = t / 20, a = t % 20;
            const float4* xp = (const float4*)(x1 + a * 20);
            const float4* tp = (const float4*)(sT11 + (nn + 5) * 20);
            float r0 = 0.f, i0 = 0.f, r1 = 0.f, i1 = 0.f;
            #pragma unroll
            for (int p = 0; p < 5; ++p) {
                float4 xv = xp[p];
                float4 t01 = tp[2*p], t23 = tp[2*p + 1];
                r0 += xv.x * t01.x + xv.y * t01.z;
                i0 += xv.x * t01.y + xv.y * t01.w;
                r1 += xv.z * t23.x + xv.w * t23.z;
                i1 += xv.z * t23.y + xv.w * t23.w;
            }
            V[nn * 22 + a] = make_float2(r0 + r1, i0 + i1);
        }
        wsync();

        // ---- G[mm][nn2] -> global, mm=0..5, nn2=-5..5; V[-n] = conj(V[n])
        for (int t = lane; t < 66; t += 64) {
            int mm = t / 11, ni2 = t % 11;
            int nn2 = ni2 - 5;
            int na = nn2 < 0 ? -nn2 : nn2;
            float s = nn2 < 0 ? -1.f : 1.f;
            const float4* vp = (const float4*)(V + na * 22);
            const float4* tp = (const float4*)(sT11 + (mm + 5) * 20);
            float r0 = 0.f, i0 = 0.f, r1 = 0.f, i1 = 0.f;
            #pragma unroll
            for (int q = 0; q < 10; ++q) {
                float4 v = vp[q], w = tp[q];
                float vy0 = s * v.y, vy1 = s * v.w;
                r0 += v.x * w.x - vy0 * w.y;
                i0 += v.x * w.y + vy0 * w.x;
                r1 += v.z * w.z - vy1 * w.w;
                i1 += v.z * w.w + vy1 * w.z;
            }
            Gg[((size_t)(b * 20 + f) * 20 + j) * 66 + t] = make_float2(r0 + r1, i0 + i1);
        }
        wsync();
    }
}

// ---------------- X2c: X2[b][k2][f] = sum_j DM2T[k2][j] * herm(G[b][f][j], k2) ----------------
__global__ __launch_bounds__(NT) void k_X2c(
    const float2* __restrict__ Gg, const float* __restrict__ gDM2T,
    const int* __restrict__ gTGIX, float2* __restrict__ X2g) {
    const int b = blockIdx.x % BT;
    const int f = blockIdx.x / BT;   // 0..19
    const int tid = threadIdx.x;
    __shared__ __align__(16) float2 sG[1320];   // [j][66]
    const float2* Gp = Gg + (size_t)(b * 20 + f) * 20 * 66;
    for (int t = tid; t < 1320; t += NT) sG[t] = Gp[t];
    __syncthreads();
    for (int k2 = tid; k2 < 286; k2 += NT) {
        int e = gTGIX[k2];
        int gi = e & 0xFFFF;
        float sg = (e >> 16) ? -1.f : 1.f;
        const float* dm = gDM2T + k2 * 20;
        float re = 0.f, im = 0.f;
        #pragma unroll
        for (int j = 0; j < 20; ++j) {
            float d = dm[j];
            float2 g = sG[j * 66 + gi];
            re += d * g.x; im += d * g.y;
        }
        X2g[b * 5720 + k2 * 20 + f] = make_float2(re, sg * im);
    }
}

// ---------------- stage 2a: Z half-items + Hermitian mirror; b-tile 8 (grid 640) ----------------
__global__ __launch_bounds__(NT) void k_Z2(
    const float2* __restrict__ X2g, const float2* __restrict__ Yk2,
    const int* __restrict__ gTABB, const int* __restrict__ gTABH,
    float2* __restrict__ Z2g) {
    const int bt = blockIdx.x & 15;       // 0..15
    const int o  = blockIdx.x >> 4;       // 0..39
    const int b0 = bt * 8;
    const int tid = threadIdx.x;

    __shared__ __align__(16) float2 sB[5792];

    const float2* Bg = Yk2 + o * 5720;
    for (int e = tid; e < 5720; e += NT) {
        int k2 = e / 20, i = e % 20;
        int p = gTABB[k2];
        int l = p & 255, r = (p >> 8) & 255, kk = p >> 16;
        sB[c_BOFF[l] + r * (40 * l + 22) + kk * 20 + i] = Bg[e];
    }
    __syncthreads();

    for (int q = tid; q < 8 * 146; q += NT) {
        int b_local = q / 146, h = q % 146;
        int ph = gTABH[h];
        int l = ph & 255, loc = ph >> 8;
        int L = 2 * l + 1;
        int mi = loc / L, ni = loc % L;
        const float4* ap = (const float4*)(X2g + (size_t)(b0 + b_local) * 5720
                                           + (c_ZB2[l] + mi * L) * 20);
        const float4* bp = (const float4*)(sB + c_BOFF[l] + ni * (40 * l + 22));
        float re = 0.f, im = 0.f;
        int n4 = 10 * L;
        for (int p4 = 0; p4 < n4; ++p4) {
            float4 a = ap[p4], y = bp[p4];
            re += a.x * y.x + a.y * y.y + a.z * y.z + a.w * y.w;
            im += a.y * y.x - a.x * y.y + a.w * y.z - a.z * y.w;
        }
        size_t base = ((size_t)(b0 + b_local) * 40 + o) * 286;
        Z2g[base + c_ZB2[l] + loc] = make_float2(re, im);
        int locm = L * L - 1 - loc;
        if (locm != loc) {
            float sg = ((mi + ni) & 1) ? -1.f : 1.f;
            Z2g[base + c_ZB2[l] + locm] = make_float2(sg * re, -sg * im);
        }
    }
}

// ---------------- stage 2b: Hermitian-halved j-loop + integrate ----------------
__global__ __launch_bounds__(NT) void k_stage2b(
    const float2* __restrict__ Z2g, const float* __restrict__ gD2R,
    const float2* __restrict__ gT12, const float2* __restrict__ gTH12,
    const float* __restrict__ gW2J, float* __restrict__ feat) {
    const int b = blockIdx.x % BT;
    const int o = blockIdx.x / BT;   // 0..39
    const int tid = threadIdx.x;
    const int wv = tid >> 6, lane = tid & 63;

    __shared__ __align__(16) float2 sZb[286];
    __shared__ __align__(16) float2 sT12[168];   // [c][n], stride 14
    __shared__ __align__(16) float2 sTH12[96];   // [a][mm], stride 8
    __shared__ __align__(16) float2 sS[4][88];   // [mm][ni] mm=0..5, stride 14
    __shared__ __align__(16) float2 sU[4][96];   // [c][mm], stride 8
    __shared__ float sredw[4];

    const float2* Zr = Z2g + ((size_t)b * 40 + o) * 286;
    for (int t = tid; t < 286; t += NT) sZb[t] = Zr[t];
    for (int t = tid; t < 132; t += NT) sT12[(t / 11) * 14 + (t % 11)] = gT12[t];
    for (int t = tid; t < 72; t += NT) sTH12[(t / 6) * 8 + (t % 6)] = gTH12[t];
    __syncthreads();

    float2* S = sS[wv];
    float2* U = sU[wv];
    float facc = 0.f;

    for (int jj = 0; jj < 3; ++jj) {
        const int j = wv + 4 * jj;

        // ---- S2[m][n], m=0..5 only
        {
            const float* dp = gD2R + j * 286;
            for (int t = lane; t < 66; t += 64) {
                int mm = t / 11, ni = t % 11;
                int n = ni - 5;
                int an = n < 0 ? -n : n;
                int lmin = mm > an ? mm : an;
                float re = 0.f, im = 0.f;
                for (int l = lmin; l < 6; ++l) {
                    int L = 2*l + 1;
                    int off = c_ZB2[l] + (mm + l) * L + (n + l);
                    float dv = dp[off];
                    float2 z = sZb[off];
                    re += dv * z.x; im += dv * z.y;
                }
                S[mm * 14 + ni] = make_float2(re, im);
            }
        }
        wsync();

        // ---- U2[m][c] = sum_n S2[m][n] T12[c][n], m=0..5; write U[c][m]
        for (int t = lane; t < 72; t += 64) {
            int mm = t / 12, c = t % 12;
            const float4* sp = (const float4*)(S + mm * 14);
            const float4* tp = (const float4*)(sT12 + c * 14);
            float re = 0.f, im = 0.f;
            #pragma unroll
            for (int p = 0; p < 5; ++p) {
                float4 s = sp[p], w = tp[p];
                re += s.x * w.x - s.y * w.y + s.z * w.z - s.w * w.w;
                im += s.x * w.y + s.y * w.x + s.z * w.w + s.w * w.z;
            }
            float2 s1 = S[mm * 14 + 10], w1 = sT12[c * 14 + 10];
            re += s1.x * w1.x - s1.y * w1.y;
            im += s1.x * w1.y + s1.y * w1.x;
            U[c * 8 + mm] = make_float2(re, im);
        }
        wsync();

        // ---- x2[a][c] = sum_{mm=0..5} Re(U2[mm][c]*TH12[a][mm]); relu; integrate
        {
            float wj = gW2J[j];
            for (int t = lane; t < 144; t += 64) {
                int a = t / 12, c = t % 12;
                const float4* up = (const float4*)(U + c * 8);
                const float4* tp = (const float4*)(sTH12 + a * 8);
                float acc = 0.f;
                #pragma unroll
                for (int p = 0; p < 3; ++p) {
                    float4 u = up[p], w = tp[p];
                    acc += u.x * w.x - u.y * w.y + u.z * w.z - u.w * w.w;
                }
                if (acc > 0.f) facc += wj * acc;
            }
        }
        wsync();
    }

    #pragma unroll
    for (int d = 32; d > 0; d >>= 1) facc += __shfl_down(facc, d, 64);
    if (lane == 0) sredw[wv] = facc;
    __syncthreads();
    if (tid == 0) {
        const float INTEG = 0.27415567780803774f;  // (2*pi/12)^2
        feat[b * 40 + o] = (sredw[0] + sredw[1] + sredw[2] + sredw[3]) * INTEG;
    }
}

__global__ void k_out(const float* __restrict__ feat, const float* __restrict__ w,
                      const float* __restrict__ bias, float* __restrict__ out) {
    int idx = blockIdx.x * blockDim.x + threadIdx.x;
    if (idx >= BT * 10) return;
    int fo = idx % 10, b = idx / 10;
    float acc = bias[fo];
    for (int o2 = 0; o2 < 40; ++o2) acc += feat[b * 40 + o2] * w[fo * 40 + o2];
    out[idx] = acc;
}

extern "C" void kernel_launch(void* const* d_in, const int* in_sizes, int n_in,
                              void* d_out, int out_size, void* d_ws, size_t ws_size,
                              hipStream_t stream) {
    (void)in_sizes; (void)n_in; (void)out_size; (void)ws_size;
    const float* x   = (const float*)d_in[0];
    const float* k1  = (const float*)d_in[1];
    const float* k2  = (const float*)d_in[2];
    const float* wO  = (const float*)d_in[3];
    const float* bO  = (const float*)d_in[4];
    float* out = (float*)d_out;

    float* ws = (float*)d_ws;
    const float2* cW60 = (const float2*)(ws + OFF_W60);
    const float*  cW2J = ws + OFF_W2J;
    const float*  cDM1 = ws + OFF_DM1;
    const float2* cY1B = (const float2*)(ws + OFF_Y1B);
    const float*  gD1R = ws + OFF_D1R;
    const float2* cY2B = (const float2*)(ws + OFF_Y2B);
    const float*  gD2R = ws + OFF_D2R;
    const float2* gT19 = (const float2*)(ws + OFF_T19U);
    const float2* gT11 = (const float2*)(ws + OFF_T11V);
    const float2* gT12 = (const float2*)(ws + OFF_T12U);
    const float2* gTH19 = (const float2*)(ws + OFF_TH19);
    const float2* gTH12 = (const float2*)(ws + OFF_TH12);
    const int*    gTABB = (const int*)(ws + OFF_TABB);
    const int*    gTABH = (const int*)(ws + OFF_TABH);
    const int*    gTAH1 = (const int*)(ws + OFF_TAH1);
    const float*  gDM2T = ws + OFF_DM2T;
    const int*    gTGIX = (const int*)(ws + OFF_TGIX);

    float2* xh   = (float2*)(ws + OFF_END);          // 128*60*19
    float2* X    = xh + BT * 60 * 19;                // 100*128
    float2* Yk1  = X + 100 * BT;                     // 100*20
    float2* Yk2  = Yk1 + 100 * 20;                   // 40*286*20
    float2* X2   = Yk2 + 40 * 286 * 20;              // 128*286*20  [b][k2][i]
    float*  feat = (float*)(X2 + (size_t)BT * 5720); // 128*40
    // Gg (3.38M f2) and Z2 (1.46M f2) have disjoint lifetimes; alias the region.
    float2* Gg   = (float2*)(feat + BT * 40);
    float2* Z2   = Gg;

    k_init<<<(N_INIT + NT - 1) / NT, NT, 0, stream>>>(ws);
    k_dft_alpha<<<(BT * 60 * 19 + NT - 1) / NT, NT, 0, stream>>>(x, cW60, xh);
    k_X1<<<(100 * BT + NT - 1) / NT, NT, 0, stream>>>(xh, cDM1, X);
    k_Yk1<<<(100 * 20 + NT - 1) / NT, NT, 0, stream>>>(k1, cY1B, Yk1);
    k_Yk2<<<292, NT, 0, stream>>>(k2, cY2B, gTABH, Yk2);
    k_stage1<<<BT * 20, NT, 0, stream>>>(X, Yk1, gD1R, gT19, gT11, gTH19, gTAH1, Gg);
    k_X2c<<<BT * 20, NT, 0, stream>>>(Gg, gDM2T, gTGIX, X2);
    k_Z2<<<640, NT, 0, stream>>>(X2, Yk2, gTABB, gTABH, Z2);
    k_stage2b<<<BT * 40, NT, 0, stream>>>(Z2, gD2R, gT12, gTH12, cW2J, feat);
    k_out<<<(BT * 10 + NT - 1) / NT, NT, 0, stream>>>(feat, wO, bO, out);
}

// Round 12
// 397.544 us; speedup vs baseline: 1.5645x; 1.1015x over previous
//
#include <hip/hip_runtime.h>
#include <cmath>

#define NT 256
#define BT 128

// ---------------- ws float-offsets for constant tables ----------------
#define OFF_W60   0          // 19*60 complex
#define OFF_E20   2280       // legacy
#define OFF_E12   2320       // legacy
#define OFF_W2J   2344       // 12 floats
#define OFF_DM1   2356       // 100*60
#define OFF_Y1B   8356       // 100*24 complex
#define OFF_D1R   13156      // [j=20][flat=1330] (2l+1)*d^l at beta1
#define OFF_DM2   39756      // legacy (dead)
#define OFF_Y2B   45476      // 286*192 complex
#define OFF_D2R   155300     // [j=12][flat=286] (2l+1)*d^l at beta2
#define OFF_T19U  158732     // 20x19 complex [c][n] e^{+2pi i n c/20}
#define OFF_T11V  159492     // 11x20 complex [r][c] e^{-2pi i (r-5) c/20}
#define OFF_T12U  159932     // 12x11 complex [c][n] e^{+2pi i n c/12}
#define OFF_TABA  160196     // legacy (dead)
#define OFF_TABB  161526     // 286 int packed
#define OFF_TH19  161812     // 20x10 complex [a][mm] f*e^{+2pi i mm a/20}
#define OFF_TH12  162212     // 12x6 complex [a][mm] f*e^{+2pi i mm a/12}
#define OFF_TABH  162356     // 146 int packed (l | loc<<8)
#define OFF_TAH1  162504     // 715 int packed (l | mm<<8 | ni<<16)
#define OFF_DM2T  163220     // [k2=286][j=20] w1[j]*d^l(beta1_j)/400
#define OFF_TGIX  168940     // 286 int: gi | (sgbit<<16)
#define OFF_QW30  169228     // 60 floats: qw(30)
#define OFF_QW10  169288     // 20 floats
#define OFF_QW6   169308     // 12 floats
#define OFF_D3B   169320     // 858 floats: wigd at s2-grid betas [k2][bi]
#define OFF_PA    170178     // 88 complex: e^{-i m alpha} [m+5][ai]
#define OFF_PG    170354     // 704 complex: e^{-i n gamma} [n+5][ai*8+ci]
#define OFF_END   171764     // 16B aligned
#define N_INIT1   1742
#define N_INIT2   109735

__constant__ int c_ZB1[10] = {0,1,10,35,84,165,286,455,680,969};
__constant__ int c_ZBH[10] = {0,1,7,22,50,95,161,252,372,525};
__constant__ int c_ZB2[6]  = {0,1,10,35,84,165};
__constant__ int c_BOFF[6] = {0,22,208,718,1712,3350};

__device__ inline void wsync() {
    __asm__ volatile("" ::: "memory");
    __builtin_amdgcn_s_waitcnt(0xC07F);
    __builtin_amdgcn_wave_barrier();
    __asm__ volatile("" ::: "memory");
}

// ---------------- fp64 helpers ----------------
__device__ inline double dipow(double x, int e) {
    double r = 1.0;
    for (int i = 0; i < e; ++i) r *= x;
    return r;
}

__device__ double wigd(const double* F, const double* Fi, int l, int mp, int m, double beta) {
    double cb = cos(beta * 0.5), sb = sin(beta * 0.5);
    int smin = m - mp; if (smin < 0) smin = 0;
    int smax = l + m;  if (l - mp < smax) smax = l - mp;
    double pref = sqrt(F[l+mp] * F[l-mp] * F[l+m] * F[l-m]);
    double sum = 0.0;
    for (int s = smin; s <= smax; ++s) {
        double t = pref * (Fi[l+m-s] * Fi[s] * Fi[mp-m+s] * Fi[l-mp-s]);
        t *= dipow(cb, 2*l + m - mp - 2*s) * dipow(sb, mp - m + 2*s);
        sum += ((mp - m + s) & 1) ? -t : t;
    }
    return sum;
}

__device__ double qwj(int bnd, int j) {
    const double PI = 3.14159265358979323846;
    double theta = PI * (2*j + 1) / (4.0 * bnd);
    double s = 0.0;
    for (int k = 0; k < bnd; ++k) s += sin(theta * (2*k + 1)) / (2*k + 1);
    return 2.0 / bnd * sin(theta) * s;
}

// ---------------- init pass 1: quadrature, D3B, phase tables ----------------
__global__ void k_init1(float* __restrict__ ws) {
    int idx = blockIdx.x * blockDim.x + threadIdx.x;
    if (idx >= N_INIT1) return;
    double F[20], Fi[20];
    F[0] = 1.0;
    #pragma unroll
    for (int i = 1; i < 20; ++i) F[i] = F[i-1] * i;
    Fi[19] = 1.0 / F[19];
    #pragma unroll
    for (int i = 18; i >= 0; --i) Fi[i] = Fi[i+1] * (i+1);
    const double PI = 3.14159265358979323846;

    if (idx < 60) {
        ws[OFF_QW30 + idx] = (float)qwj(30, idx);
    } else if (idx < 80) {
        ws[OFF_QW10 + idx - 60] = (float)qwj(10, idx - 60);
    } else if (idx < 92) {
        ws[OFF_QW6 + idx - 80] = (float)qwj(6, idx - 80);
    } else if (idx < 950) {                 // D3B [k2][bi]
        int e = idx - 92; int k2 = e / 3, bi = e % 3;
        int l = 0; while (l < 5 && k2 >= c_ZB2[l+1]) ++l;
        int L = 2*l + 1, loc = k2 - c_ZB2[l];
        int m = loc / L - l, n = loc % L - l;
        double beta = (bi + 1) * (PI / 8.0) / 3.0;
        ws[OFF_D3B + e] = (float)wigd(F, Fi, l, m, n, beta);
    } else if (idx < 1038) {                // PA [m+5][ai]
        int e = idx - 950; int m = e / 8 - 5, ai = e % 8;
        double ph = -(double)m * (2.0 * PI * ai / 8.0);
        ws[OFF_PA + 2*e]     = (float)cos(ph);
        ws[OFF_PA + 2*e + 1] = (float)sin(ph);
    } else {                                // PG [n+5][ai*8+ci]
        int e = idx - 1038; int n = e / 64 - 5, g2 = e % 64, ai = g2 / 8, ci = g2 % 8;
        double alpha = 2.0 * PI * ai / 8.0;
        double gamma = (-2.0 * PI + ci * (PI / 2.0)) - alpha;
        double ph = -(double)n * gamma;
        ws[OFF_PG + 2*e]     = (float)cos(ph);
        ws[OFF_PG + 2*e + 1] = (float)sin(ph);
    }
}

// ---------------- init pass 2: big tables via pass-1 lookups ----------------
__global__ void k_init2(float* __restrict__ ws) {
    int idx = blockIdx.x * blockDim.x + threadIdx.x;
    if (idx >= N_INIT2) return;
    double F[20], Fi[20];
    F[0] = 1.0;
    #pragma unroll
    for (int i = 1; i < 20; ++i) F[i] = F[i-1] * i;
    Fi[19] = 1.0 / F[19];
    #pragma unroll
    for (int i = 18; i >= 0; --i) Fi[i] = Fi[i+1] * (i+1);
    const double PI = 3.14159265358979323846;

    if (idx < 1140) {                       // W60
        int r = idx / 60, a = idx % 60;
        double ang = -2.0 * PI * (double)((r - 9) * a) / 60.0;
        ws[OFF_W60 + 2*idx]     = (float)cos(ang);
        ws[OFF_W60 + 2*idx + 1] = (float)sin(ang);
    } else if (idx < 1160) {
        int t = idx - 1140;
        double ang = 2.0 * PI * t / 20.0;
        ws[OFF_E20 + 2*t]     = (float)cos(ang);
        ws[OFF_E20 + 2*t + 1] = (float)sin(ang);
    } else if (idx < 1172) {
        int t = idx - 1160;
        double ang = 2.0 * PI * t / 12.0;
        ws[OFF_E12 + 2*t]     = (float)cos(ang);
        ws[OFF_E12 + 2*t + 1] = (float)sin(ang);
    } else if (idx < 1184) {                // W2J from QW6
        int j = idx - 1172;
        ws[OFF_W2J + j] = ws[OFF_QW6 + j];
    } else if (idx < 7184) {                // DM1[k][j] using QW30
        int e = idx - 1184; int k = e / 60, j = e % 60;
        int l = 0; while ((l + 1) * (l + 1) <= k) ++l;
        int m = k - l*l - l;
        double beta = PI * (2*j + 1) / 120.0;
        ws[OFF_DM1 + e] = (float)((double)ws[OFF_QW30 + j] * wigd(F, Fi, l, m, 0, beta));
    } else if (idx < 9584) {                // Y1B
        int e = idx - 7184; int k = e / 24, g = e % 24;
        int l = 0; while ((l + 1) * (l + 1) <= k) ++l;
        int m = k - l*l - l;
        int bi = g / 8, ai = g % 8;
        double beta  = (bi + 1) * (PI / 8.0) / 3.0;
        double alpha = 2.0 * PI * ai / 8.0;
        double d = wigd(F, Fi, l, m, 0, beta);
        double ph = -(double)m * alpha;
        ws[OFF_Y1B + 2*e]     = (float)(d * cos(ph));
        ws[OFF_Y1B + 2*e + 1] = (float)(d * sin(ph));
    } else if (idx < 36184) {               // D1R [j][flat], prescaled by (2l+1)
        int e = idx - 9584; int j = e / 1330, t = e % 1330;
        int l = 0; while (l < 9 && t >= c_ZB1[l+1]) ++l;
        int L = 2*l + 1, loc = t - c_ZB1[l];
        int mi = loc / L, ni = loc % L;
        double beta = PI * (2*j + 1) / 40.0;
        ws[OFF_D1R + e] = (float)((double)L * wigd(F, Fi, l, mi - l, ni - l, beta));
    } else if (idx < 41904) {
        // legacy DM2 — dead, skip
    } else if (idx < 96816) {               // Y2B via D3B + PA + PG
        int e = idx - 41904; int k2 = e / 192, g = e % 192;
        int l = 0; while (l < 5 && k2 >= c_ZB2[l+1]) ++l;
        int L = 2*l + 1, loc = k2 - c_ZB2[l];
        int m = loc / L - l, n = loc % L - l;
        int bi = g / 64, ai = (g / 8) % 8, ci = g % 8;
        float d = ws[OFF_D3B + k2 * 3 + bi];
        const float2 pa = ((const float2*)(ws + OFF_PA))[(m + 5) * 8 + ai];
        const float2 pg = ((const float2*)(ws + OFF_PG))[(n + 5) * 64 + ai * 8 + ci];
        ws[OFF_Y2B + 2*e]     = d * (pa.x * pg.x - pa.y * pg.y);
        ws[OFF_Y2B + 2*e + 1] = d * (pa.x * pg.y + pa.y * pg.x);
    } else if (idx < 100248) {              // D2R [j][flat], prescaled by (2l+1)
        int e = idx - 96816; int j = e / 286, t = e % 286;
        int l = 0; while (l < 5 && t >= c_ZB2[l+1]) ++l;
        int L = 2*l + 1, loc = t - c_ZB2[l];
        int mi = loc / L, ni = loc % L;
        double beta = PI * (2*j + 1) / 24.0;
        ws[OFF_D2R + e] = (float)((double)L * wigd(F, Fi, l, mi - l, ni - l, beta));
    } else if (idx < 100628) {              // T19U [c][n]
        int e = idx - 100248; int c = e / 19, n = e % 19 - 9;
        double ang = 2.0 * PI * (double)(n * c) / 20.0;
        ws[OFF_T19U + 2*e]     = (float)cos(ang);
        ws[OFF_T19U + 2*e + 1] = (float)sin(ang);
    } else if (idx < 100848) {              // T11V [r][c]
        int e = idx - 100628; int r = e / 20, c = e % 20;
        double ang = -2.0 * PI * (double)((r - 5) * c) / 20.0;
        ws[OFF_T11V + 2*e]     = (float)cos(ang);
        ws[OFF_T11V + 2*e + 1] = (float)sin(ang);
    } else if (idx < 100980) {              // T12U [c][n]
        int e = idx - 100848; int c = e / 11, n = e % 11 - 5;
        double ang = 2.0 * PI * (double)(n * c) / 12.0;
        ws[OFF_T12U + 2*e]     = (float)cos(ang);
        ws[OFF_T12U + 2*e + 1] = (float)sin(ang);
    } else if (idx < 102310) {
        // legacy TABA — dead, skip
    } else if (idx < 102596) {              // TABB
        int t = idx - 102310;
        int l = 0; while (l < 5 && t >= c_ZB2[l+1]) ++l;
        int L = 2*l + 1, loc = t - c_ZB2[l];
        ((int*)ws)[OFF_TABB + t] = l | ((loc / L) << 8) | ((loc % L) << 16);
    } else if (idx < 102796) {              // TH19 [a][mm]
        int e = idx - 102596; int a = e / 10, mm = e % 10;
        double f = (mm == 0) ? 1.0 : 2.0;
        double ang = 2.0 * PI * (double)(mm * a) / 20.0;
        ws[OFF_TH19 + 2*e]     = (float)(f * cos(ang));
        ws[OFF_TH19 + 2*e + 1] = (float)(f * sin(ang));
    } else if (idx < 102868) {              // TH12 [a][mm]
        int e = idx - 102796; int a = e / 6, mm = e % 6;
        double f = (mm == 0) ? 1.0 : 2.0;
        double ang = 2.0 * PI * (double)(mm * a) / 12.0;
        ws[OFF_TH12 + 2*e]     = (float)(f * cos(ang));
        ws[OFF_TH12 + 2*e + 1] = (float)(f * sin(ang));
    } else if (idx < 103014) {              // TABH
        int t = idx - 102868;
        int l = 0, cum = 0, loc = 0;
        for (; l < 6; ++l) {
            int L = 2*l + 1, h = (L*L + 1) / 2;
            if (t < cum + h) { loc = t - cum; break; }
            cum += h;
        }
        ((int*)ws)[OFF_TABH + t] = l | (loc << 8);
    } else if (idx < 103729) {              // TAH1
        int t = idx - 103014;
        int l = 0; while (l < 9 && t >= c_ZBH[l+1]) ++l;
        int L = 2*l + 1, loc = t - c_ZBH[l];
        ((int*)ws)[OFF_TAH1 + t] = l | ((loc / L) << 8) | ((loc % L) << 16);
    } else if (idx < 109449) {              // DM2T [k2][j] using QW10, /400
        int e = idx - 103729; int k2 = e / 20, j = e % 20;
        int l = 0; while (l < 5 && k2 >= c_ZB2[l+1]) ++l;
        int L = 2*l + 1, loc = k2 - c_ZB2[l];
        int mi = loc / L, ni = loc % L;
        double beta = PI * (2*j + 1) / 40.0;
        ws[OFF_DM2T + e] = (float)((double)ws[OFF_QW10 + j] *
                                   wigd(F, Fi, l, mi - l, ni - l, beta) / 400.0);
    } else {                                // TGIX
        int t = idx - 109449;
        int l = 0; while (l < 5 && t >= c_ZB2[l+1]) ++l;
        int L = 2*l + 1, loc = t - c_ZB2[l];
        int m = loc / L - l, n = loc % L - l;
        int gi, sgbit;
        if (m >= 0) { gi = m * 11 + (n + 5); sgbit = 0; }
        else        { gi = (-m) * 11 + (5 - n); sgbit = 1; }
        ((int*)ws)[OFF_TGIX + t] = gi | (sgbit << 16);
    }
}

// ---------------- small pipeline kernels ----------------
__global__ void k_dft_alpha(const float* __restrict__ x, const float2* __restrict__ W60,
                            float2* __restrict__ xh) {
    int idx = blockIdx.x * blockDim.x + threadIdx.x;
    if (idx >= BT * 60 * 19) return;
    int r = idx % 19;
    int j = (idx / 19) % 60;
    int b = idx / (19 * 60);
    const float* xr = x + (b * 60 + j) * 60;
    const float2* wr = W60 + r * 60;
    float re = 0.f, im = 0.f;
    for (int a = 0; a < 60; ++a) {
        float v = xr[a];
        float2 w = wr[a];
        re += v * w.x; im += v * w.y;
    }
    xh[idx] = make_float2(re * (1.f / 60.f), im * (1.f / 60.f));
}

// fused: blocks 0..49 -> X1; blocks 50..57 -> Yk1
__global__ void k_X1Y1(const float2* __restrict__ xh, const float* __restrict__ DM1,
                       float2* __restrict__ X, const float* __restrict__ k1,
                       const float2* __restrict__ Y1B, float2* __restrict__ Yk1) {
    int bid = blockIdx.x;
    if (bid < 50) {
        int idx = bid * NT + threadIdx.x;
        if (idx >= 100 * BT) return;
        int b = idx % BT, k = idx / BT;
        int l = 0; while ((l + 1) * (l + 1) <= k) ++l;
        int r = (k - l*l - l) + 9;
        float re = 0.f, im = 0.f;
        for (int j = 0; j < 60; ++j) {
            float d = DM1[k * 60 + j];
            float2 v = xh[(b * 60 + j) * 19 + r];
            re += d * v.x; im += d * v.y;
        }
        X[k * BT + b] = make_float2(re, im);
    } else {
        int idx = (bid - 50) * NT + threadIdx.x;
        if (idx >= 100 * 20) return;
        int o = idx % 20, k = idx / 20;
        float re = 0.f, im = 0.f;
        for (int g = 0; g < 24; ++g) {
            float2 y = Y1B[k * 24 + g];
            float w = k1[o * 24 + g];
            re += y.x * w; im += y.y * w;
        }
        const float SC1 = 0.20412414523193154f;
        Yk1[idx] = make_float2(re * SC1, im * SC1);
    }
}

// Yk2 layout: [o][k2][i]; grid 292
__global__ __launch_bounds__(NT) void k_Yk2(const float* __restrict__ k2in,
                                            const float2* __restrict__ Y2B,
                                            const int* __restrict__ gTABH,
                                            float2* __restrict__ Yk2) {
    const int h = blockIdx.x >> 1;
    const int half = blockIdx.x & 1;
    const int tid = threadIdx.x;
    int ph = gTABH[h];
    int l = ph & 255, loc = ph >> 8;
    int L = 2 * l + 1;
    int mi = loc / L, ni = loc % L;
    int k2  = c_ZB2[l] + loc;
    int locm = L * L - 1 - loc;
    int k2m = c_ZB2[l] + locm;
    float par = ((mi + ni) & 1) ? -1.f : 1.f;

    __shared__ __align__(16) float2 sY[192];
    for (int t = tid; t < 192; t += NT) sY[t] = Y2B[k2 * 192 + t];
    __syncthreads();
    const float4* sY4 = (const float4*)sY;
    const float SC2 = 0.016137430609197573f;
    for (int t = half * 400 + tid; t < half * 400 + 400; t += NT) {
        int o = t / 20, i = t % 20;
        const float4* kp = (const float4*)(k2in + (i * 40 + o) * 192);
        float re = 0.f, im = 0.f;
        #pragma unroll 4
        for (int p = 0; p < 48; ++p) {
            float4 w = kp[p];
            float4 y01 = sY4[2*p], y23 = sY4[2*p + 1];
            re += w.x * y01.x + w.y * y01.z + w.z * y23.x + w.w * y23.z;
            im += w.x * y01.y + w.y * y01.w + w.z * y23.y + w.w * y23.w;
        }
        re *= SC2; im *= SC2;
        Yk2[(o * 286 + k2) * 20 + i] = make_float2(re, im);
        if (k2m != k2)
            Yk2[(o * 286 + k2m) * 20 + i] = make_float2(par * re, -par * im);
    }
}

// ---------------- stage 1: parity-halved U and x1 phases ----------------
__global__ __launch_bounds__(NT) void k_stage1(
    const float2* __restrict__ X, const float2* __restrict__ Yk1,
    const float* __restrict__ gD1R,
    const float2* __restrict__ gT19, const float2* __restrict__ gT11,
    const float2* __restrict__ gTH19,
    const int* __restrict__ gTAH1, float2* __restrict__ Gg) {
    const int b = blockIdx.x % BT;
    const int f = blockIdx.x / BT;
    const int tid = threadIdx.x;
    const int wv = tid >> 6, lane = tid & 63;

    __shared__ __align__(16) float2 sZ[715];
    __shared__ __align__(16) float2 sT19[440];   // [c][n], stride 22
    __shared__ __align__(16) float2 sTH19[280];  // [a][mm], stride 14
    __shared__ __align__(16) float2 sT11[220];   // [r][c], stride 20
    __shared__ __align__(16) float2 sA[4][224];  // S(10x22) | x1(400f)
    __shared__ __align__(16) float2 sB[4][280];  // U(20x14) | V(6x22)

    for (int t = tid; t < 380; t += NT) sT19[(t / 19) * 22 + (t % 19)] = gT19[t];
    for (int t = tid; t < 200; t += NT) sTH19[(t / 10) * 14 + (t % 10)] = gTH19[t];
    for (int t = tid; t < 220; t += NT) sT11[t] = gT11[t];
    for (int t = tid; t < 715; t += NT) {
        int p = gTAH1[t];
        int l = p & 255, mm = (p >> 8) & 255, ni = p >> 16;
        float2 a = X[(l*l + l + mm) * BT + b];
        float2 y = Yk1[(l*l + ni) * 20 + f];
        sZ[t] = make_float2(a.x * y.x + a.y * y.y, a.y * y.x - a.x * y.y);
    }
    __syncthreads();

    float2* S   = sA[wv];            // [mm][ni], stride 22
    float2* U   = sB[wv];            // [c][mm], stride 14
    float*  x1  = (float*)sA[wv];    // [a][c], stride 20 floats
    float2* V   = sB[wv];            // [nn][a], stride 22

    for (int jj = 0; jj < 5; ++jj) {
        const int j = wv + 4 * jj;

        // ---- S[m][n], m=0..9 only
        {
            const float* dp = gD1R + j * 1330;
            for (int t = lane; t < 190; t += 64) {
                int mm = t / 19, ni = t % 19;
                int n = ni - 9;
                int an = n < 0 ? -n : n;
                int lmin = mm > an ? mm : an;
                float re = 0.f, im = 0.f;
                for (int l = lmin; l < 10; ++l) {
                    int L = 2*l + 1;
                    float dv = dp[c_ZB1[l] + (mm + l) * L + (n + l)];
                    float2 z = sZ[c_ZBH[l] + mm * L + (n + l)];
                    re += dv * z.x; im += dv * z.y;
                }
                S[mm * 22 + ni] = make_float2(re, im);
            }
        }
        wsync();

        // ---- U[mm][c] & U[mm][c+10] via n-parity split; items (mm, c in 0..9)
        // f4 p covers ni=2p (n odd -> O) in .xy and ni=2p+1 (n even -> E) in .zw
        for (int t = lane; t < 100; t += 64) {
            int mm = t / 10, c = t % 10;
            const float4* sp = (const float4*)(S + mm * 22);
            const float4* tp = (const float4*)(sT19 + c * 22);
            float re_e = 0.f, im_e = 0.f, re_o = 0.f, im_o = 0.f;
            #pragma unroll
            for (int p = 0; p < 9; ++p) {
                float4 s = sp[p], w = tp[p];
                re_o += s.x * w.x - s.y * w.y;  im_o += s.x * w.y + s.y * w.x;
                re_e += s.z * w.z - s.w * w.w;  im_e += s.z * w.w + s.w * w.z;
            }
            {   // ni = 18 -> n = 9 (odd)
                float2 s1 = S[mm * 22 + 18], w1 = sT19[c * 22 + 18];
                re_o += s1.x * w1.x - s1.y * w1.y;
                im_o += s1.x * w1.y + s1.y * w1.x;
            }
            U[c * 14 + mm]        = make_float2(re_e + re_o, im_e + im_o);
            U[(c + 10) * 14 + mm] = make_float2(re_e - re_o, im_e - im_o);
        }
        wsync();

        // ---- x1 quad via mm-parity: items (ap in 0..9, cp in 0..9) -> 4 outputs
        // f4 p covers mm=2p (even -> E) in .xy and mm=2p+1 (odd -> O) in .zw
        for (int t = lane; t < 100; t += 64) {
            int cp = t % 10, ap = t / 10;
            const float4* u0 = (const float4*)(U + cp * 14);
            const float4* u1 = (const float4*)(U + (cp + 10) * 14);
            const float4* tp = (const float4*)(sTH19 + ap * 14);
            float e0 = 0.f, o0 = 0.f, e1 = 0.f, o1 = 0.f;
            #pragma unroll
            for (int p = 0; p < 5; ++p) {
                float4 w = tp[p];
                float4 ua = u0[p], ub = u1[p];
                e0 += ua.x * w.x - ua.y * w.y;
                o0 += ua.z * w.z - ua.w * w.w;
                e1 += ub.x * w.x - ub.y * w.y;
                o1 += ub.z * w.z - ub.w * w.w;
            }
            float v;
            v = e0 + o0; x1[ap * 20 + cp]             = v > 0.f ? v : 0.f;
            v = e0 - o0; x1[(ap + 10) * 20 + cp]      = v > 0.f ? v : 0.f;
            v = e1 + o1; x1[ap * 20 + cp + 10]        = v > 0.f ? v : 0.f;
            v = e1 - o1; x1[(ap + 10) * 20 + cp + 10] = v > 0.f ? v : 0.f;
        }
        wsync();

        // ---- V[nn][a] = sum_c x1[a][c] e^{-2pi i nn c/20}, nn=0..5
        for (int t = lane; t < 120; t += 64) {
            int nn = t / 20, a = t % 20;
            const float4* xp = (const float4*)(x1 + a * 20);
            const float4* tp = (const float4*)(sT11 + (nn + 5) * 20);
            float r0 = 0.f, i0 = 0.f, r1 = 0.f, i1 = 0.f;
            #pragma unroll
            for (int p = 0; p < 5; ++p) {
                float4 xv = xp[p];
                float4 t01 = tp[2*p], t23 = tp[2*p + 1];
                r0 += xv.x * t01.x + xv.y * t01.z;
                i0 += xv.x * t01.y + xv.y * t01.w;
                r1 += xv.z * t23.x + xv.w * t23.z;
                i1 += xv.z * t23.y + xv.w * t23.w;
            }
            V[nn * 22 + a] = make_float2(r0 + r1, i0 + i1);
        }
        wsync();

        // ---- G[mm][nn2] -> global
        for (int t = lane; t < 66; t += 64) {
            int mm = t / 11, ni2 = t % 11;
            int nn2 = ni2 - 5;
            int na = nn2 < 0 ? -nn2 : nn2;
            float s = nn2 < 0 ? -1.f : 1.f;
            const float4* vp = (const float4*)(V + na * 22);
            const float4* tp = (const float4*)(sT11 + (mm + 5) * 20);
            float r0 = 0.f, i0 = 0.f, r1 = 0.f, i1 = 0.f;
            #pragma unroll
            for (int q = 0; q < 10; ++q) {
                float4 v = vp[q], w = tp[q];
                float vy0 = s * v.y, vy1 = s * v.w;
                r0 += v.x * w.x - vy0 * w.y;
                i0 += v.x * w.y + vy0 * w.x;
                r1 += v.z * w.z - vy1 * w.w;
                i1 += v.z * w.w + vy1 * w.z;
            }
            Gg[((size_t)(b * 20 + f) * 20 + j) * 66 + t] = make_float2(r0 + r1, i0 + i1);
        }
        wsync();
    }
}

// ---------------- X2c ----------------
__global__ __launch_bounds__(NT) void k_X2c(
    const float2* __restrict__ Gg, const float* __restrict__ gDM2T,
    const int* __restrict__ gTGIX, float2* __restrict__ X2g) {
    const int b = blockIdx.x % BT;
    const int f = blockIdx.x / BT;
    const int tid = threadIdx.x;
    __shared__ __align__(16) float2 sG[1320];
    const float2* Gp = Gg + (size_t)(b * 20 + f) * 20 * 66;
    for (int t = tid; t < 1320; t += NT) sG[t] = Gp[t];
    __syncthreads();
    for (int k2 = tid; k2 < 286; k2 += NT) {
        int e = gTGIX[k2];
        int gi = e & 0xFFFF;
        float sg = (e >> 16) ? -1.f : 1.f;
        const float* dm = gDM2T + k2 * 20;
        float re = 0.f, im = 0.f;
        #pragma unroll
        for (int j = 0; j < 20; ++j) {
            float d = dm[j];
            float2 g = sG[j * 66 + gi];
            re += d * g.x; im += d * g.y;
        }
        X2g[b * 5720 + k2 * 20 + f] = make_float2(re, sg * im);
    }
}

// ---------------- stage 2a: l-split (part0: l<=4, part1: l=5); grid 1280 ----------------
__global__ __launch_bounds__(NT) void k_Z2(
    const float2* __restrict__ X2g, const float2* __restrict__ Yk2,
    const int* __restrict__ gTABB, const int* __restrict__ gTABH,
    float2* __restrict__ Z2g) {
    const int bt   = blockIdx.x & 15;      // 0..15
    const int part = (blockIdx.x >> 4) & 1;
    const int o    = blockIdx.x >> 5;      // 0..39
    const int b0 = bt * 8;
    const int tid = threadIdx.x;

    __shared__ __align__(16) float2 sB[3350];  // part0: 3350 f2; part1: 2442 f2

    const int sub  = part ? 3350 : 0;
    const int stN  = part ? 2420 : 3300;       // staged f2 count
    const int k2b  = part ? 165 : 0;
    const float2* Bg = Yk2 + o * 5720 + k2b * 20;
    for (int e = tid; e < stN; e += NT) {
        int k2 = k2b + e / 20, i = e % 20;
        int p = gTABB[k2];
        int l = p & 255, r = (p >> 8) & 255, kk = p >> 16;
        sB[c_BOFF[l] - sub + r * (40 * l + 22) + kk * 20 + i] = Bg[e];
    }
    __syncthreads();

    const int perb  = part ? 61 : 85;
    const int hbase = part ? 85 : 0;
    for (int q = tid; q < 8 * perb; q += NT) {
        int b_local = q / perb, h = hbase + q % perb;
        int ph = gTABH[h];
        int l = ph & 255, loc = ph >> 8;
        int L = 2 * l + 1;
        int mi = loc / L, ni = loc % L;
        const float4* ap = (const float4*)(X2g + (size_t)(b0 + b_local) * 5720
                                           + (c_ZB2[l] + mi * L) * 20);
        const float4* bp = (const float4*)(sB + c_BOFF[l] - sub + ni * (40 * l + 22));
        float re = 0.f, im = 0.f;
        int n4 = 10 * L;
        for (int p4 = 0; p4 < n4; ++p4) {
            float4 a = ap[p4], y = bp[p4];
            re += a.x * y.x + a.y * y.y + a.z * y.z + a.w * y.w;
            im += a.y * y.x - a.x * y.y + a.w * y.z - a.z * y.w;
        }
        size_t base = ((size_t)(b0 + b_local) * 40 + o) * 286;
        Z2g[base + c_ZB2[l] + loc] = make_float2(re, im);
        int locm = L * L - 1 - loc;
        if (locm != loc) {
            float sg = ((mi + ni) & 1) ? -1.f : 1.f;
            Z2g[base + c_ZB2[l] + locm] = make_float2(sg * re, -sg * im);
        }
    }
}

// ---------------- stage 2b ----------------
__global__ __launch_bounds__(NT) void k_stage2b(
    const float2* __restrict__ Z2g, const float* __restrict__ gD2R,
    const float2* __restrict__ gT12, const float2* __restrict__ gTH12,
    const float* __restrict__ gW2J, float* __restrict__ feat) {
    const int b = blockIdx.x % BT;
    const int o = blockIdx.x / BT;
    const int tid = threadIdx.x;
    const int wv = tid >> 6, lane = tid & 63;

    __shared__ __align__(16) float2 sZb[286];
    __shared__ __align__(16) float2 sT12[168];
    __shared__ __align__(16) float2 sTH12[96];
    __shared__ __align__(16) float2 sS[4][88];
    __shared__ __align__(16) float2 sU[4][96];
    __shared__ float sredw[4];

    const float2* Zr = Z2g + ((size_t)b * 40 + o) * 286;
    for (int t = tid; t < 286; t += NT) sZb[t] = Zr[t];
    for (int t = tid; t < 132; t += NT) sT12[(t / 11) * 14 + (t % 11)] = gT12[t];
    for (int t = tid; t < 72; t += NT) sTH12[(t / 6) * 8 + (t % 6)] = gTH12[t];
    __syncthreads();

    float2* S = sS[wv];
    float2* U = sU[wv];
    float facc = 0.f;

    for (int jj = 0; jj < 3; ++jj) {
        const int j = wv + 4 * jj;

        {
            const float* dp = gD2R + j * 286;
            for (int t = lane; t < 66; t += 64) {
                int mm = t / 11, ni = t % 11;
                int n = ni - 5;
                int an = n < 0 ? -n : n;
                int lmin = mm > an ? mm : an;
                float re = 0.f, im = 0.f;
                for (int l = lmin; l < 6; ++l) {
                    int L = 2*l + 1;
                    int off = c_ZB2[l] + (mm + l) * L + (n + l);
                    float dv = dp[off];
                    float2 z = sZb[off];
                    re += dv * z.x; im += dv * z.y;
                }
                S[mm * 14 + ni] = make_float2(re, im);
            }
        }
        wsync();

        for (int t = lane; t < 72; t += 64) {
            int mm = t / 12, c = t % 12;
            const float4* sp = (const float4*)(S + mm * 14);
            const float4* tp = (const float4*)(sT12 + c * 14);
            float re = 0.f, im = 0.f;
            #pragma unroll
            for (int p = 0; p < 5; ++p) {
                float4 s = sp[p], w = tp[p];
                re += s.x * w.x - s.y * w.y + s.z * w.z - s.w * w.w;
                im += s.x * w.y + s.y * w.x + s.z * w.w + s.w * w.z;
            }
            float2 s1 = S[mm * 14 + 10], w1 = sT12[c * 14 + 10];
            re += s1.x * w1.x - s1.y * w1.y;
            im += s1.x * w1.y + s1.y * w1.x;
            U[c * 8 + mm] = make_float2(re, im);
        }
        wsync();

        {
            float wj = gW2J[j];
            for (int t = lane; t < 144; t += 64) {
                int a = t / 12, c = t % 12;
                const float4* up = (const float4*)(U + c * 8);
                const float4* tp = (const float4*)(sTH12 + a * 8);
                float acc = 0.f;
                #pragma unroll
                for (int p = 0; p < 3; ++p) {
                    float4 u = up[p], w = tp[p];
                    acc += u.x * w.x - u.y * w.y + u.z * w.z - u.w * w.w;
                }
                if (acc > 0.f) facc += wj * acc;
            }
        }
        wsync();
    }

    #pragma unroll
    for (int d = 32; d > 0; d >>= 1) facc += __shfl_down(facc, d, 64);
    if (lane == 0) sredw[wv] = facc;
    __syncthreads();
    if (tid == 0) {
        const float INTEG = 0.27415567780803774f;
        feat[b * 40 + o] = (sredw[0] + sredw[1] + sredw[2] + sredw[3]) * INTEG;
    }
}

__global__ void k_out(const float* __restrict__ feat, const float* __restrict__ w,
                      const float* __restrict__ bias, float* __restrict__ out) {
    int idx = blockIdx.x * blockDim.x + threadIdx.x;
    if (idx >= BT * 10) return;
    int fo = idx % 10, b = idx / 10;
    float acc = bias[fo];
    for (int o2 = 0; o2 < 40; ++o2) acc += feat[b * 40 + o2] * w[fo * 40 + o2];
    out[idx] = acc;
}

extern "C" void kernel_launch(void* const* d_in, const int* in_sizes, int n_in,
                              void* d_out, int out_size, void* d_ws, size_t ws_size,
                              hipStream_t stream) {
    (void)in_sizes; (void)n_in; (void)out_size; (void)ws_size;
    const float* x   = (const float*)d_in[0];
    const float* k1  = (const float*)d_in[1];
    const float* k2  = (const float*)d_in[2];
    const float* wO  = (const float*)d_in[3];
    const float* bO  = (const float*)d_in[4];
    float* out = (float*)d_out;

    float* ws = (float*)d_ws;
    const float2* cW60 = (const float2*)(ws + OFF_W60);
    const float*  cW2J = ws + OFF_W2J;
    const float*  cDM1 = ws + OFF_DM1;
    const float2* cY1B = (const float2*)(ws + OFF_Y1B);
    const float*  gD1R = ws + OFF_D1R;
    const float2* cY2B = (const float2*)(ws + OFF_Y2B);
    const float*  gD2R = ws + OFF_D2R;
    const float2* gT19 = (const float2*)(ws + OFF_T19U);
    const float2* gT11 = (const float2*)(ws + OFF_T11V);
    const float2* gT12 = (const float2*)(ws + OFF_T12U);
    const float2* gTH19 = (const float2*)(ws + OFF_TH19);
    const float2* gTH12 = (const float2*)(ws + OFF_TH12);
    const int*    gTABB = (const int*)(ws + OFF_TABB);
    const int*    gTABH = (const int*)(ws + OFF_TABH);
    const int*    gTAH1 = (const int*)(ws + OFF_TAH1);
    const float*  gDM2T = ws + OFF_DM2T;
    const int*    gTGIX = (const int*)(ws + OFF_TGIX);

    float2* xh   = (float2*)(ws + OFF_END);          // 128*60*19
    float2* X    = xh + BT * 60 * 19;                // 100*128
    float2* Yk1  = X + 100 * BT;                     // 100*20
    float2* Yk2  = Yk1 + 100 * 20;                   // 40*286*20
    float2* X2   = Yk2 + 40 * 286 * 20;              // 128*286*20
    float*  feat = (float*)(X2 + (size_t)BT * 5720); // 128*40
    float2* Gg   = (float2*)(feat + BT * 40);        // aliased with Z2 (disjoint lifetimes)
    float2* Z2   = Gg;

    k_init1<<<(N_INIT1 + NT - 1) / NT, NT, 0, stream>>>(ws);
    k_init2<<<(N_INIT2 + NT - 1) / NT, NT, 0, stream>>>(ws);
    k_dft_alpha<<<(BT * 60 * 19 + NT - 1) / NT, NT, 0, stream>>>(x, cW60, xh);
    k_X1Y1<<<58, NT, 0, stream>>>(xh, cDM1, X, k1, cY1B, Yk1);
    k_Yk2<<<292, NT, 0, stream>>>(k2, cY2B, gTABH, Yk2);
    k_stage1<<<BT * 20, NT, 0, stream>>>(X, Yk1, gD1R, gT19, gT11, gTH19, gTAH1, Gg);
    k_X2c<<<BT * 20, NT, 0, stream>>>(Gg, gDM2T, gTGIX, X2);
    k_Z2<<<1280, NT, 0, stream>>>(X2, Yk2, gTABB, gTABH, Z2);
    k_stage2b<<<BT * 40, NT, 0, stream>>>(Z2, gD2R, gT12, gTH12, cW2J, feat);
    k_out<<<(BT * 10 + NT - 1) / NT, NT, 0, stream>>>(feat, wO, bO, out);
}

// Round 13
// 363.469 us; speedup vs baseline: 1.7112x; 1.0937x over previous
//
#include <hip/hip_runtime.h>
#include <cmath>

#define NT 256
#define BT 128

// ---------------- ws float-offsets for constant tables ----------------
#define OFF_W60   0          // 19*60 complex
#define OFF_E20   2280       // legacy
#define OFF_E12   2320       // legacy
#define OFF_W2J   2344       // 12 floats
#define OFF_DM1   2356       // 100*60
#define OFF_Y1B   8356       // 100*24 complex
#define OFF_D1R   13156      // [j=20][flat=1330] (2l+1)*d^l at beta1
#define OFF_DM2   39756      // legacy (dead)
#define OFF_Y2B   45476      // 286*192 complex
#define OFF_D2R   155300     // [j=12][flat=286] (2l+1)*d^l at beta2
#define OFF_T19U  158732     // 20x19 complex [c][n] e^{+2pi i n c/20}
#define OFF_T11V  159492     // 11x20 complex [r][c] e^{-2pi i (r-5) c/20}
#define OFF_T12U  159932     // 12x11 complex [c][n] e^{+2pi i n c/12}
#define OFF_TABA  160196     // legacy (dead)
#define OFF_TABB  161526     // 286 int packed
#define OFF_TH19  161812     // 20x10 complex [a][mm] f*e^{+2pi i mm a/20}
#define OFF_TH12  162212     // 12x6 complex [a][mm] f*e^{+2pi i mm a/12}
#define OFF_TABH  162356     // 146 int packed (l | loc<<8)
#define OFF_TAH1  162504     // 715 int packed (l | mm<<8 | ni<<16)
#define OFF_DM2T  163220     // [k2=286][j=20] w1[j]*d^l(beta1_j)/400
#define OFF_TGIX  168940     // 286 int: gi | (sgbit<<16)
#define OFF_QW30  169228     // 60 floats
#define OFF_QW10  169288     // 20 floats
#define OFF_QW6   169308     // 12 floats
#define OFF_D3B   169320     // 858 floats
#define OFF_PA    170178     // 88 complex
#define OFF_PG    170354     // 704 complex
#define OFF_END   171764
#define N_INIT1   1742
#define N_INIT2   109735

__constant__ int c_ZB1[10] = {0,1,10,35,84,165,286,455,680,969};
__constant__ int c_ZBH[10] = {0,1,7,22,50,95,161,252,372,525};
__constant__ int c_ZB2[6]  = {0,1,10,35,84,165};
__constant__ int c_BOFF[6] = {0,22,208,718,1712,3350};

__device__ inline void wsync() {
    __asm__ volatile("" ::: "memory");
    __builtin_amdgcn_s_waitcnt(0xC07F);
    __builtin_amdgcn_wave_barrier();
    __asm__ volatile("" ::: "memory");
}

// ---------------- fp64 helpers ----------------
__device__ inline double dipow(double x, int e) {
    double r = 1.0;
    for (int i = 0; i < e; ++i) r *= x;
    return r;
}

__device__ double wigd(const double* F, const double* Fi, int l, int mp, int m, double beta) {
    double cb = cos(beta * 0.5), sb = sin(beta * 0.5);
    int smin = m - mp; if (smin < 0) smin = 0;
    int smax = l + m;  if (l - mp < smax) smax = l - mp;
    double pref = sqrt(F[l+mp] * F[l-mp] * F[l+m] * F[l-m]);
    double sum = 0.0;
    for (int s = smin; s <= smax; ++s) {
        double t = pref * (Fi[l+m-s] * Fi[s] * Fi[mp-m+s] * Fi[l-mp-s]);
        t *= dipow(cb, 2*l + m - mp - 2*s) * dipow(sb, mp - m + 2*s);
        sum += ((mp - m + s) & 1) ? -t : t;
    }
    return sum;
}

__device__ double qwj(int bnd, int j) {
    const double PI = 3.14159265358979323846;
    double theta = PI * (2*j + 1) / (4.0 * bnd);
    double s = 0.0;
    for (int k = 0; k < bnd; ++k) s += sin(theta * (2*k + 1)) / (2*k + 1);
    return 2.0 / bnd * sin(theta) * s;
}

// ---------------- init pass 1 ----------------
__global__ void k_init1(float* __restrict__ ws) {
    int idx = blockIdx.x * blockDim.x + threadIdx.x;
    if (idx >= N_INIT1) return;
    double F[20], Fi[20];
    F[0] = 1.0;
    #pragma unroll
    for (int i = 1; i < 20; ++i) F[i] = F[i-1] * i;
    Fi[19] = 1.0 / F[19];
    #pragma unroll
    for (int i = 18; i >= 0; --i) Fi[i] = Fi[i+1] * (i+1);
    const double PI = 3.14159265358979323846;

    if (idx < 60) {
        ws[OFF_QW30 + idx] = (float)qwj(30, idx);
    } else if (idx < 80) {
        ws[OFF_QW10 + idx - 60] = (float)qwj(10, idx - 60);
    } else if (idx < 92) {
        ws[OFF_QW6 + idx - 80] = (float)qwj(6, idx - 80);
    } else if (idx < 950) {                 // D3B [k2][bi]
        int e = idx - 92; int k2 = e / 3, bi = e % 3;
        int l = 0; while (l < 5 && k2 >= c_ZB2[l+1]) ++l;
        int L = 2*l + 1, loc = k2 - c_ZB2[l];
        int m = loc / L - l, n = loc % L - l;
        double beta = (bi + 1) * (PI / 8.0) / 3.0;
        ws[OFF_D3B + e] = (float)wigd(F, Fi, l, m, n, beta);
    } else if (idx < 1038) {                // PA
        int e = idx - 950; int m = e / 8 - 5, ai = e % 8;
        double ph = -(double)m * (2.0 * PI * ai / 8.0);
        ws[OFF_PA + 2*e]     = (float)cos(ph);
        ws[OFF_PA + 2*e + 1] = (float)sin(ph);
    } else {                                // PG
        int e = idx - 1038; int n = e / 64 - 5, g2 = e % 64, ai = g2 / 8, ci = g2 % 8;
        double alpha = 2.0 * PI * ai / 8.0;
        double gamma = (-2.0 * PI + ci * (PI / 2.0)) - alpha;
        double ph = -(double)n * gamma;
        ws[OFF_PG + 2*e]     = (float)cos(ph);
        ws[OFF_PG + 2*e + 1] = (float)sin(ph);
    }
}

// ---------------- init pass 2 ----------------
__global__ void k_init2(float* __restrict__ ws) {
    int idx = blockIdx.x * blockDim.x + threadIdx.x;
    if (idx >= N_INIT2) return;
    double F[20], Fi[20];
    F[0] = 1.0;
    #pragma unroll
    for (int i = 1; i < 20; ++i) F[i] = F[i-1] * i;
    Fi[19] = 1.0 / F[19];
    #pragma unroll
    for (int i = 18; i >= 0; --i) Fi[i] = Fi[i+1] * (i+1);
    const double PI = 3.14159265358979323846;

    if (idx < 1140) {                       // W60
        int r = idx / 60, a = idx % 60;
        double ang = -2.0 * PI * (double)((r - 9) * a) / 60.0;
        ws[OFF_W60 + 2*idx]     = (float)cos(ang);
        ws[OFF_W60 + 2*idx + 1] = (float)sin(ang);
    } else if (idx < 1160) {
        int t = idx - 1140;
        double ang = 2.0 * PI * t / 20.0;
        ws[OFF_E20 + 2*t]     = (float)cos(ang);
        ws[OFF_E20 + 2*t + 1] = (float)sin(ang);
    } else if (idx < 1172) {
        int t = idx - 1160;
        double ang = 2.0 * PI * t / 12.0;
        ws[OFF_E12 + 2*t]     = (float)cos(ang);
        ws[OFF_E12 + 2*t + 1] = (float)sin(ang);
    } else if (idx < 1184) {
        int j = idx - 1172;
        ws[OFF_W2J + j] = ws[OFF_QW6 + j];
    } else if (idx < 7184) {                // DM1[k][j]
        int e = idx - 1184; int k = e / 60, j = e % 60;
        int l = 0; while ((l + 1) * (l + 1) <= k) ++l;
        int m = k - l*l - l;
        double beta = PI * (2*j + 1) / 120.0;
        ws[OFF_DM1 + e] = (float)((double)ws[OFF_QW30 + j] * wigd(F, Fi, l, m, 0, beta));
    } else if (idx < 9584) {                // Y1B
        int e = idx - 7184; int k = e / 24, g = e % 24;
        int l = 0; while ((l + 1) * (l + 1) <= k) ++l;
        int m = k - l*l - l;
        int bi = g / 8, ai = g % 8;
        double beta  = (bi + 1) * (PI / 8.0) / 3.0;
        double alpha = 2.0 * PI * ai / 8.0;
        double d = wigd(F, Fi, l, m, 0, beta);
        double ph = -(double)m * alpha;
        ws[OFF_Y1B + 2*e]     = (float)(d * cos(ph));
        ws[OFF_Y1B + 2*e + 1] = (float)(d * sin(ph));
    } else if (idx < 36184) {               // D1R
        int e = idx - 9584; int j = e / 1330, t = e % 1330;
        int l = 0; while (l < 9 && t >= c_ZB1[l+1]) ++l;
        int L = 2*l + 1, loc = t - c_ZB1[l];
        int mi = loc / L, ni = loc % L;
        double beta = PI * (2*j + 1) / 40.0;
        ws[OFF_D1R + e] = (float)((double)L * wigd(F, Fi, l, mi - l, ni - l, beta));
    } else if (idx < 41904) {
        // dead
    } else if (idx < 96816) {               // Y2B via D3B + PA + PG
        int e = idx - 41904; int k2 = e / 192, g = e % 192;
        int l = 0; while (l < 5 && k2 >= c_ZB2[l+1]) ++l;
        int L = 2*l + 1, loc = k2 - c_ZB2[l];
        int m = loc / L - l, n = loc % L - l;
        int bi = g / 64, ai = (g / 8) % 8, ci = g % 8;
        float d = ws[OFF_D3B + k2 * 3 + bi];
        const float2 pa = ((const float2*)(ws + OFF_PA))[(m + 5) * 8 + ai];
        const float2 pg = ((const float2*)(ws + OFF_PG))[(n + 5) * 64 + ai * 8 + ci];
        ws[OFF_Y2B + 2*e]     = d * (pa.x * pg.x - pa.y * pg.y);
        ws[OFF_Y2B + 2*e + 1] = d * (pa.x * pg.y + pa.y * pg.x);
    } else if (idx < 100248) {              // D2R
        int e = idx - 96816; int j = e / 286, t = e % 286;
        int l = 0; while (l < 5 && t >= c_ZB2[l+1]) ++l;
        int L = 2*l + 1, loc = t - c_ZB2[l];
        int mi = loc / L, ni = loc % L;
        double beta = PI * (2*j + 1) / 24.0;
        ws[OFF_D2R + e] = (float)((double)L * wigd(F, Fi, l, mi - l, ni - l, beta));
    } else if (idx < 100628) {              // T19U
        int e = idx - 100248; int c = e / 19, n = e % 19 - 9;
        double ang = 2.0 * PI * (double)(n * c) / 20.0;
        ws[OFF_T19U + 2*e]     = (float)cos(ang);
        ws[OFF_T19U + 2*e + 1] = (float)sin(ang);
    } else if (idx < 100848) {              // T11V
        int e = idx - 100628; int r = e / 20, c = e % 20;
        double ang = -2.0 * PI * (double)((r - 5) * c) / 20.0;
        ws[OFF_T11V + 2*e]     = (float)cos(ang);
        ws[OFF_T11V + 2*e + 1] = (float)sin(ang);
    } else if (idx < 100980) {              // T12U
        int e = idx - 100848; int c = e / 11, n = e % 11 - 5;
        double ang = 2.0 * PI * (double)(n * c) / 12.0;
        ws[OFF_T12U + 2*e]     = (float)cos(ang);
        ws[OFF_T12U + 2*e + 1] = (float)sin(ang);
    } else if (idx < 102310) {
        // dead
    } else if (idx < 102596) {              // TABB
        int t = idx - 102310;
        int l = 0; while (l < 5 && t >= c_ZB2[l+1]) ++l;
        int L = 2*l + 1, loc = t - c_ZB2[l];
        ((int*)ws)[OFF_TABB + t] = l | ((loc / L) << 8) | ((loc % L) << 16);
    } else if (idx < 102796) {              // TH19
        int e = idx - 102596; int a = e / 10, mm = e % 10;
        double f = (mm == 0) ? 1.0 : 2.0;
        double ang = 2.0 * PI * (double)(mm * a) / 20.0;
        ws[OFF_TH19 + 2*e]     = (float)(f * cos(ang));
        ws[OFF_TH19 + 2*e + 1] = (float)(f * sin(ang));
    } else if (idx < 102868) {              // TH12
        int e = idx - 102796; int a = e / 6, mm = e % 6;
        double f = (mm == 0) ? 1.0 : 2.0;
        double ang = 2.0 * PI * (double)(mm * a) / 12.0;
        ws[OFF_TH12 + 2*e]     = (float)(f * cos(ang));
        ws[OFF_TH12 + 2*e + 1] = (float)(f * sin(ang));
    } else if (idx < 103014) {              // TABH
        int t = idx - 102868;
        int l = 0, cum = 0, loc = 0;
        for (; l < 6; ++l) {
            int L = 2*l + 1, h = (L*L + 1) / 2;
            if (t < cum + h) { loc = t - cum; break; }
            cum += h;
        }
        ((int*)ws)[OFF_TABH + t] = l | (loc << 8);
    } else if (idx < 103729) {              // TAH1
        int t = idx - 103014;
        int l = 0; while (l < 9 && t >= c_ZBH[l+1]) ++l;
        int L = 2*l + 1, loc = t - c_ZBH[l];
        ((int*)ws)[OFF_TAH1 + t] = l | ((loc / L) << 8) | ((loc % L) << 16);
    } else if (idx < 109449) {              // DM2T
        int e = idx - 103729; int k2 = e / 20, j = e % 20;
        int l = 0; while (l < 5 && k2 >= c_ZB2[l+1]) ++l;
        int L = 2*l + 1, loc = k2 - c_ZB2[l];
        int mi = loc / L, ni = loc % L;
        double beta = PI * (2*j + 1) / 40.0;
        ws[OFF_DM2T + e] = (float)((double)ws[OFF_QW10 + j] *
                                   wigd(F, Fi, l, mi - l, ni - l, beta) / 400.0);
    } else {                                // TGIX
        int t = idx - 109449;
        int l = 0; while (l < 5 && t >= c_ZB2[l+1]) ++l;
        int L = 2*l + 1, loc = t - c_ZB2[l];
        int m = loc / L - l, n = loc % L - l;
        int gi, sgbit;
        if (m >= 0) { gi = m * 11 + (n + 5); sgbit = 0; }
        else        { gi = (-m) * 11 + (5 - n); sgbit = 1; }
        ((int*)ws)[OFF_TGIX + t] = gi | (sgbit << 16);
    }
}

// ---------------- fused front-end: blocks 0..127 = per-b (dft_alpha + X1); 128..135 = Yk1 ----------------
__global__ __launch_bounds__(NT) void k_front(
    const float* __restrict__ x, const float2* __restrict__ W60,
    const float* __restrict__ DM1, float2* __restrict__ X,
    const float* __restrict__ k1, const float2* __restrict__ Y1B,
    float2* __restrict__ Yk1) {
    const int bid = blockIdx.x;
    const int tid = threadIdx.x;
    if (bid < BT) {
        const int b = bid;
        __shared__ __align__(16) float  sx[3600];
        __shared__ __align__(16) float2 sW[1140];
        __shared__ __align__(16) float2 sxh[1140];
        for (int t = tid; t < 900; t += NT)
            ((float4*)sx)[t] = ((const float4*)(x + b * 3600))[t];
        for (int t = tid; t < 1140; t += NT) sW[t] = W60[t];
        __syncthreads();
        for (int t = tid; t < 1140; t += NT) {
            int r = t % 19, j = t / 19;
            const float* xr = sx + j * 60;
            const float2* wr = sW + r * 60;
            float re = 0.f, im = 0.f;
            for (int a = 0; a < 60; ++a) {
                float v = xr[a];
                float2 w = wr[a];
                re += v * w.x; im += v * w.y;
            }
            sxh[j * 19 + r] = make_float2(re * (1.f / 60.f), im * (1.f / 60.f));
        }
        __syncthreads();
        for (int k = tid; k < 100; k += NT) {
            int l = 0; while ((l + 1) * (l + 1) <= k) ++l;
            int r = (k - l*l - l) + 9;
            float re = 0.f, im = 0.f;
            for (int j = 0; j < 60; ++j) {
                float d = DM1[k * 60 + j];
                float2 v = sxh[j * 19 + r];
                re += d * v.x; im += d * v.y;
            }
            X[k * BT + b] = make_float2(re, im);
        }
    } else {
        int idx = (bid - BT) * NT + tid;
        if (idx >= 100 * 20) return;
        int o = idx % 20, k = idx / 20;
        float re = 0.f, im = 0.f;
        for (int g = 0; g < 24; ++g) {
            float2 y = Y1B[k * 24 + g];
            float w = k1[o * 24 + g];
            re += y.x * w; im += y.y * w;
        }
        const float SC1 = 0.20412414523193154f;
        Yk1[idx] = make_float2(re * SC1, im * SC1);
    }
}

// Yk2 layout: [o][k2][i]; grid 292
__global__ __launch_bounds__(NT) void k_Yk2(const float* __restrict__ k2in,
                                            const float2* __restrict__ Y2B,
                                            const int* __restrict__ gTABH,
                                            float2* __restrict__ Yk2) {
    const int h = blockIdx.x >> 1;
    const int half = blockIdx.x & 1;
    const int tid = threadIdx.x;
    int ph = gTABH[h];
    int l = ph & 255, loc = ph >> 8;
    int L = 2 * l + 1;
    int mi = loc / L, ni = loc % L;
    int k2  = c_ZB2[l] + loc;
    int locm = L * L - 1 - loc;
    int k2m = c_ZB2[l] + locm;
    float par = ((mi + ni) & 1) ? -1.f : 1.f;

    __shared__ __align__(16) float2 sY[192];
    for (int t = tid; t < 192; t += NT) sY[t] = Y2B[k2 * 192 + t];
    __syncthreads();
    const float4* sY4 = (const float4*)sY;
    const float SC2 = 0.016137430609197573f;
    for (int t = half * 400 + tid; t < half * 400 + 400; t += NT) {
        int o = t / 20, i = t % 20;
        const float4* kp = (const float4*)(k2in + (i * 40 + o) * 192);
        float re = 0.f, im = 0.f;
        #pragma unroll 4
        for (int p = 0; p < 48; ++p) {
            float4 w = kp[p];
            float4 y01 = sY4[2*p], y23 = sY4[2*p + 1];
            re += w.x * y01.x + w.y * y01.z + w.z * y23.x + w.w * y23.z;
            im += w.x * y01.y + w.y * y01.w + w.z * y23.y + w.w * y23.w;
        }
        re *= SC2; im *= SC2;
        Yk2[(o * 286 + k2) * 20 + i] = make_float2(re, im);
        if (k2m != k2)
            Yk2[(o * 286 + k2m) * 20 + i] = make_float2(par * re, -par * im);
    }
}

// ---------------- stage 1: parity-halved; G kept in LDS; fused DM2T contraction -> X2 ----------------
__global__ __launch_bounds__(NT) void k_stage1(
    const float2* __restrict__ X, const float2* __restrict__ Yk1,
    const float* __restrict__ gD1R,
    const float2* __restrict__ gT19, const float2* __restrict__ gT11,
    const float2* __restrict__ gTH19,
    const int* __restrict__ gTAH1, const float* __restrict__ gDM2T,
    const int* __restrict__ gTGIX, float2* __restrict__ X2g) {
    const int b = blockIdx.x % BT;
    const int f = blockIdx.x / BT;
    const int tid = threadIdx.x;
    const int wv = tid >> 6, lane = tid & 63;

    __shared__ __align__(16) float2 sZ[715];
    __shared__ __align__(16) float2 sT19[440];   // [c][n], stride 22
    __shared__ __align__(16) float2 sTH19[280];  // [a][mm], stride 14
    __shared__ __align__(16) float2 sT11[220];   // [r][c], stride 20
    __shared__ __align__(16) float2 sGall[1320]; // [j][66]
    __shared__ __align__(16) float2 sA[4][224];  // S(10x22) | x1(400f)
    __shared__ __align__(16) float2 sB[4][280];  // U(20x14) | V(6x22)

    for (int t = tid; t < 380; t += NT) sT19[(t / 19) * 22 + (t % 19)] = gT19[t];
    for (int t = tid; t < 200; t += NT) sTH19[(t / 10) * 14 + (t % 10)] = gTH19[t];
    for (int t = tid; t < 220; t += NT) sT11[t] = gT11[t];
    for (int t = tid; t < 715; t += NT) {
        int p = gTAH1[t];
        int l = p & 255, mm = (p >> 8) & 255, ni = p >> 16;
        float2 a = X[(l*l + l + mm) * BT + b];
        float2 y = Yk1[(l*l + ni) * 20 + f];
        sZ[t] = make_float2(a.x * y.x + a.y * y.y, a.y * y.x - a.x * y.y);
    }
    __syncthreads();

    float2* S   = sA[wv];            // [mm][ni], stride 22
    float2* U   = sB[wv];            // [c][mm], stride 14
    float*  x1  = (float*)sA[wv];    // [a][c], stride 20 floats
    float2* V   = sB[wv];            // [nn][a], stride 22

    for (int jj = 0; jj < 5; ++jj) {
        const int j = wv + 4 * jj;

        // ---- S[m][n], m=0..9 only
        {
            const float* dp = gD1R + j * 1330;
            for (int t = lane; t < 190; t += 64) {
                int mm = t / 19, ni = t % 19;
                int n = ni - 9;
                int an = n < 0 ? -n : n;
                int lmin = mm > an ? mm : an;
                float re = 0.f, im = 0.f;
                for (int l = lmin; l < 10; ++l) {
                    int L = 2*l + 1;
                    float dv = dp[c_ZB1[l] + (mm + l) * L + (n + l)];
                    float2 z = sZ[c_ZBH[l] + mm * L + (n + l)];
                    re += dv * z.x; im += dv * z.y;
                }
                S[mm * 22 + ni] = make_float2(re, im);
            }
        }
        wsync();

        // ---- U via n-parity split
        for (int t = lane; t < 100; t += 64) {
            int mm = t / 10, c = t % 10;
            const float4* sp = (const float4*)(S + mm * 22);
            const float4* tp = (const float4*)(sT19 + c * 22);
            float re_e = 0.f, im_e = 0.f, re_o = 0.f, im_o = 0.f;
            #pragma unroll
            for (int p = 0; p < 9; ++p) {
                float4 s = sp[p], w = tp[p];
                re_o += s.x * w.x - s.y * w.y;  im_o += s.x * w.y + s.y * w.x;
                re_e += s.z * w.z - s.w * w.w;  im_e += s.z * w.w + s.w * w.z;
            }
            {
                float2 s1 = S[mm * 22 + 18], w1 = sT19[c * 22 + 18];
                re_o += s1.x * w1.x - s1.y * w1.y;
                im_o += s1.x * w1.y + s1.y * w1.x;
            }
            U[c * 14 + mm]        = make_float2(re_e + re_o, im_e + im_o);
            U[(c + 10) * 14 + mm] = make_float2(re_e - re_o, im_e - im_o);
        }
        wsync();

        // ---- x1 quad via mm-parity
        for (int t = lane; t < 100; t += 64) {
            int cp = t % 10, ap = t / 10;
            const float4* u0 = (const float4*)(U + cp * 14);
            const float4* u1 = (const float4*)(U + (cp + 10) * 14);
            const float4* tp = (const float4*)(sTH19 + ap * 14);
            float e0 = 0.f, o0 = 0.f, e1 = 0.f, o1 = 0.f;
            #pragma unroll
            for (int p = 0; p < 5; ++p) {
                float4 w = tp[p];
                float4 ua = u0[p], ub = u1[p];
                e0 += ua.x * w.x - ua.y * w.y;
                o0 += ua.z * w.z - ua.w * w.w;
                e1 += ub.x * w.x - ub.y * w.y;
                o1 += ub.z * w.z - ub.w * w.w;
            }
            float v;
            v = e0 + o0; x1[ap * 20 + cp]             = v > 0.f ? v : 0.f;
            v = e0 - o0; x1[(ap + 10) * 20 + cp]      = v > 0.f ? v : 0.f;
            v = e1 + o1; x1[ap * 20 + cp + 10]        = v > 0.f ? v : 0.f;
            v = e1 - o1; x1[(ap + 10) * 20 + cp + 10] = v > 0.f ? v : 0.f;
        }
        wsync();

        // ---- V[nn][a]
        for (int t = lane; t < 120; t += 64) {
            int nn = t / 20, a = t % 20;
            const float4* xp = (const float4*)(x1 + a * 20);
            const float4* tp = (const float4*)(sT11 + (nn + 5) * 20);
            float r0 = 0.f, i0 = 0.f, r1 = 0.f, i1 = 0.f;
            #pragma unroll
            for (int p = 0; p < 5; ++p) {
                float4 xv = xp[p];
                float4 t01 = tp[2*p], t23 = tp[2*p + 1];
                r0 += xv.x * t01.x + xv.y * t01.z;
                i0 += xv.x * t01.y + xv.y * t01.w;
                r1 += xv.z * t23.x + xv.w * t23.z;
                i1 += xv.z * t23.y + xv.w * t23.w;
            }
            V[nn * 22 + a] = make_float2(r0 + r1, i0 + i1);
        }
        wsync();

        // ---- G[mm][nn2] -> sGall[j]
        for (int t = lane; t < 66; t += 64) {
            int mm = t / 11, ni2 = t % 11;
            int nn2 = ni2 - 5;
            int na = nn2 < 0 ? -nn2 : nn2;
            float s = nn2 < 0 ? -1.f : 1.f;
            const float4* vp = (const float4*)(V + na * 22);
            const float4* tp = (const float4*)(sT11 + (mm + 5) * 20);
            float r0 = 0.f, i0 = 0.f, r1 = 0.f, i1 = 0.f;
            #pragma unroll
            for (int q = 0; q < 10; ++q) {
                float4 v = vp[q], w = tp[q];
                float vy0 = s * v.y, vy1 = s * v.w;
                r0 += v.x * w.x - vy0 * w.y;
                i0 += v.x * w.y + vy0 * w.x;
                r1 += v.z * w.z - vy1 * w.w;
                i1 += v.z * w.w + vy1 * w.z;
            }
            sGall[j * 66 + t] = make_float2(r0 + r1, i0 + i1);
        }
        wsync();
    }
    __syncthreads();

    // ---- X2[k2] = sum_j DM2T[k2][j] * herm(G[j], k2)
    for (int k2 = tid; k2 < 286; k2 += NT) {
        int e = gTGIX[k2];
        int gi = e & 0xFFFF;
        float sg = (e >> 16) ? -1.f : 1.f;
        const float* dm = gDM2T + k2 * 20;
        float re = 0.f, im = 0.f;
        #pragma unroll
        for (int j = 0; j < 20; ++j) {
            float d = dm[j];
            float2 g = sGall[j * 66 + gi];
            re += d * g.x; im += d * g.y;
        }
        X2g[b * 5720 + k2 * 20 + f] = make_float2(re, sg * im);
    }
}

// ---------------- stage 2a: l-split; grid 1280 ----------------
__global__ __launch_bounds__(NT) void k_Z2(
    const float2* __restrict__ X2g, const float2* __restrict__ Yk2,
    const int* __restrict__ gTABB, const int* __restrict__ gTABH,
    float2* __restrict__ Z2g) {
    const int bt   = blockIdx.x & 15;
    const int part = (blockIdx.x >> 4) & 1;
    const int o    = blockIdx.x >> 5;
    const int b0 = bt * 8;
    const int tid = threadIdx.x;

    __shared__ __align__(16) float2 sB[3350];

    const int sub  = part ? 3350 : 0;
    const int stN  = part ? 2420 : 3300;
    const int k2b  = part ? 165 : 0;
    const float2* Bg = Yk2 + o * 5720 + k2b * 20;
    for (int e = tid; e < stN; e += NT) {
        int k2 = k2b + e / 20, i = e % 20;
        int p = gTABB[k2];
        int l = p & 255, r = (p >> 8) & 255, kk = p >> 16;
        sB[c_BOFF[l] - sub + r * (40 * l + 22) + kk * 20 + i] = Bg[e];
    }
    __syncthreads();

    const int perb  = part ? 61 : 85;
    const int hbase = part ? 85 : 0;
    for (int q = tid; q < 8 * perb; q += NT) {
        int b_local = q / perb, h = hbase + q % perb;
        int ph = gTABH[h];
        int l = ph & 255, loc = ph >> 8;
        int L = 2 * l + 1;
        int mi = loc / L, ni = loc % L;
        const float4* ap = (const float4*)(X2g + (size_t)(b0 + b_local) * 5720
                                           + (c_ZB2[l] + mi * L) * 20);
        const float4* bp = (const float4*)(sB + c_BOFF[l] - sub + ni * (40 * l + 22));
        float re = 0.f, im = 0.f;
        int n4 = 10 * L;
        for (int p4 = 0; p4 < n4; ++p4) {
            float4 a = ap[p4], y = bp[p4];
            re += a.x * y.x + a.y * y.y + a.z * y.z + a.w * y.w;
            im += a.y * y.x - a.x * y.y + a.w * y.z - a.z * y.w;
        }
        size_t base = ((size_t)(b0 + b_local) * 40 + o) * 286;
        Z2g[base + c_ZB2[l] + loc] = make_float2(re, im);
        int locm = L * L - 1 - loc;
        if (locm != loc) {
            float sg = ((mi + ni) & 1) ? -1.f : 1.f;
            Z2g[base + c_ZB2[l] + locm] = make_float2(sg * re, -sg * im);
        }
    }
}

// ---------------- stage 2b: NT=128, 2 waves x 6 j ----------------
__global__ __launch_bounds__(128) void k_stage2b(
    const float2* __restrict__ Z2g, const float* __restrict__ gD2R,
    const float2* __restrict__ gT12, const float2* __restrict__ gTH12,
    const float* __restrict__ gW2J, float* __restrict__ feat) {
    const int b = blockIdx.x % BT;
    const int o = blockIdx.x / BT;
    const int tid = threadIdx.x;
    const int wv = tid >> 6, lane = tid & 63;

    __shared__ __align__(16) float2 sZb[286];
    __shared__ __align__(16) float2 sT12[168];
    __shared__ __align__(16) float2 sTH12[96];
    __shared__ __align__(16) float2 sS[2][88];
    __shared__ __align__(16) float2 sU[2][96];
    __shared__ float sredw[2];

    const float2* Zr = Z2g + ((size_t)b * 40 + o) * 286;
    for (int t = tid; t < 286; t += 128) sZb[t] = Zr[t];
    for (int t = tid; t < 132; t += 128) sT12[(t / 11) * 14 + (t % 11)] = gT12[t];
    for (int t = tid; t < 72; t += 128) sTH12[(t / 6) * 8 + (t % 6)] = gTH12[t];
    __syncthreads();

    float2* S = sS[wv];
    float2* U = sU[wv];
    float facc = 0.f;

    for (int jj = 0; jj < 6; ++jj) {
        const int j = wv + 2 * jj;

        {
            const float* dp = gD2R + j * 286;
            for (int t = lane; t < 66; t += 64) {
                int mm = t / 11, ni = t % 11;
                int n = ni - 5;
                int an = n < 0 ? -n : n;
                int lmin = mm > an ? mm : an;
                float re = 0.f, im = 0.f;
                for (int l = lmin; l < 6; ++l) {
                    int L = 2*l + 1;
                    int off = c_ZB2[l] + (mm + l) * L + (n + l);
                    float dv = dp[off];
                    float2 z = sZb[off];
                    re += dv * z.x; im += dv * z.y;
                }
                S[mm * 14 + ni] = make_float2(re, im);
            }
        }
        wsync();

        for (int t = lane; t < 72; t += 64) {
            int mm = t / 12, c = t % 12;
            const float4* sp = (const float4*)(S + mm * 14);
            const float4* tp = (const float4*)(sT12 + c * 14);
            float re = 0.f, im = 0.f;
            #pragma unroll
            for (int p = 0; p < 5; ++p) {
                float4 s = sp[p], w = tp[p];
                re += s.x * w.x - s.y * w.y + s.z * w.z - s.w * w.w;
                im += s.x * w.y + s.y * w.x + s.z * w.w + s.w * w.z;
            }
            float2 s1 = S[mm * 14 + 10], w1 = sT12[c * 14 + 10];
            re += s1.x * w1.x - s1.y * w1.y;
            im += s1.x * w1.y + s1.y * w1.x;
            U[c * 8 + mm] = make_float2(re, im);
        }
        wsync();

        {
            float wj = gW2J[j];
            for (int t = lane; t < 144; t += 64) {
                int a = t / 12, c = t % 12;
                const float4* up = (const float4*)(U + c * 8);
                const float4* tp = (const float4*)(sTH12 + a * 8);
                float acc = 0.f;
                #pragma unroll
                for (int p = 0; p < 3; ++p) {
                    float4 u = up[p], w = tp[p];
                    acc += u.x * w.x - u.y * w.y + u.z * w.z - u.w * w.w;
                }
                if (acc > 0.f) facc += wj * acc;
            }
        }
        wsync();
    }

    #pragma unroll
    for (int d = 32; d > 0; d >>= 1) facc += __shfl_down(facc, d, 64);
    if (lane == 0) sredw[wv] = facc;
    __syncthreads();
    if (tid == 0) {
        const float INTEG = 0.27415567780803774f;
        feat[b * 40 + o] = (sredw[0] + sredw[1]) * INTEG;
    }
}

__global__ void k_out(const float* __restrict__ feat, const float* __restrict__ w,
                      const float* __restrict__ bias, float* __restrict__ out) {
    int idx = blockIdx.x * blockDim.x + threadIdx.x;
    if (idx >= BT * 10) return;
    int fo = idx % 10, b = idx / 10;
    float acc = bias[fo];
    for (int o2 = 0; o2 < 40; ++o2) acc += feat[b * 40 + o2] * w[fo * 40 + o2];
    out[idx] = acc;
}

extern "C" void kernel_launch(void* const* d_in, const int* in_sizes, int n_in,
                              void* d_out, int out_size, void* d_ws, size_t ws_size,
                              hipStream_t stream) {
    (void)in_sizes; (void)n_in; (void)out_size; (void)ws_size;
    const float* x   = (const float*)d_in[0];
    const float* k1  = (const float*)d_in[1];
    const float* k2  = (const float*)d_in[2];
    const float* wO  = (const float*)d_in[3];
    const float* bO  = (const float*)d_in[4];
    float* out = (float*)d_out;

    float* ws = (float*)d_ws;
    const float2* cW60 = (const float2*)(ws + OFF_W60);
    const float*  cW2J = ws + OFF_W2J;
    const float*  cDM1 = ws + OFF_DM1;
    const float2* cY1B = (const float2*)(ws + OFF_Y1B);
    const float*  gD1R = ws + OFF_D1R;
    const float2* cY2B = (const float2*)(ws + OFF_Y2B);
    const float*  gD2R = ws + OFF_D2R;
    const float2* gT19 = (const float2*)(ws + OFF_T19U);
    const float2* gT11 = (const float2*)(ws + OFF_T11V);
    const float2* gT12 = (const float2*)(ws + OFF_T12U);
    const float2* gTH19 = (const float2*)(ws + OFF_TH19);
    const float2* gTH12 = (const float2*)(ws + OFF_TH12);
    const int*    gTABB = (const int*)(ws + OFF_TABB);
    const int*    gTABH = (const int*)(ws + OFF_TABH);
    const int*    gTAH1 = (const int*)(ws + OFF_TAH1);
    const float*  gDM2T = ws + OFF_DM2T;
    const int*    gTGIX = (const int*)(ws + OFF_TGIX);

    float2* X    = (float2*)(ws + OFF_END);          // 100*128
    float2* Yk1  = X + 100 * BT;                     // 100*20
    float2* Yk2  = Yk1 + 100 * 20;                   // 40*286*20
    float2* X2   = Yk2 + 40 * 286 * 20;              // 128*286*20
    float*  feat = (float*)(X2 + (size_t)BT * 5720); // 128*40
    float2* Z2   = (float2*)(feat + BT * 40);        // 128*40*286

    k_init1<<<(N_INIT1 + NT - 1) / NT, NT, 0, stream>>>(ws);
    k_init2<<<(N_INIT2 + NT - 1) / NT, NT, 0, stream>>>(ws);
    k_front<<<BT + 8, NT, 0, stream>>>(x, cW60, cDM1, X, k1, cY1B, Yk1);
    k_Yk2<<<292, NT, 0, stream>>>(k2, cY2B, gTABH, Yk2);
    k_stage1<<<BT * 20, NT, 0, stream>>>(X, Yk1, gD1R, gT19, gT11, gTH19, gTAH1,
                                         gDM2T, gTGIX, X2);
    k_Z2<<<1280, NT, 0, stream>>>(X2, Yk2, gTABB, gTABH, Z2);
    k_stage2b<<<BT * 40, 128, 0, stream>>>(Z2, gD2R, gT12, gTH12, cW2J, feat);
    k_out<<<(BT * 10 + NT - 1) / NT, NT, 0, stream>>>(feat, wO, bO, out);
}